// Round 9
// baseline (240.184 us; speedup 1.0000x reference)
//
#include <hip/hip_runtime.h>
#include <hip/hip_fp8.h>
#include <math.h>

#define NN 3072
#define NU 1024
#define NI 2048
#define DD 128
#define BB 8192
#define GAMMA_F 0.2f

#define SCALE_A 524288.0f                // 2^19
#define F8SCALE2 1.9073486328125e-06f    // 2^-19  (C*2^38 -> A2*2^19 for fp8)
#define DESCALE38 3.637978807091713e-12f // 2^-38  (C -> true A^k values)

// packed fp8 layout: [k/64][row][k%64]; one k-block = NN rows x 64 B
#define KBLK ((size_t)NN * 64)

typedef __attribute__((ext_vector_type(4))) float f32x4;
typedef __attribute__((ext_vector_type(16))) float f32x16;
typedef __attribute__((ext_vector_type(4))) int i32x4;
typedef __attribute__((ext_vector_type(8))) int i32x8;

static __device__ inline unsigned short bf16bits(float x) {
  union { unsigned u; float f; } cv;
  cv.f = x;
  unsigned r = cv.u + 0x7fff + ((cv.u >> 16) & 1);  // RNE
  return (unsigned short)(r >> 16);
}

// pack 4 floats -> 4 fp8 e4m3 (OCP) bytes
static __device__ inline unsigned pk4_f8(float a, float b, float c, float d) {
#if defined(__has_builtin)
#if __has_builtin(__builtin_amdgcn_cvt_pk_fp8_f32)
  int p = __builtin_amdgcn_cvt_pk_fp8_f32(a, b, 0, false);
  p = __builtin_amdgcn_cvt_pk_fp8_f32(c, d, p, true);
  return (unsigned)p;
#else
  return (unsigned)__hip_fp8_e4m3(a).__x | ((unsigned)__hip_fp8_e4m3(b).__x << 8) |
         ((unsigned)__hip_fp8_e4m3(c).__x << 16) |
         ((unsigned)__hip_fp8_e4m3(d).__x << 24);
#endif
#else
  return (unsigned)__hip_fp8_e4m3(a).__x | ((unsigned)__hip_fp8_e4m3(b).__x << 8) |
         ((unsigned)__hip_fp8_e4m3(c).__x << 16) |
         ((unsigned)__hip_fp8_e4m3(d).__x << 24);
#endif
}

static __device__ inline void atomAddF(float* p, float v) {
#if defined(__has_builtin)
#if __has_builtin(__builtin_amdgcn_global_atomic_fadd_f32)
  __builtin_amdgcn_global_atomic_fadd_f32(
      (__attribute__((address_space(1))) float*)p, v);
#else
  unsafeAtomicAdd(p, v);
#endif
#else
  unsafeAtomicAdd(p, v);
#endif
}

static __device__ inline float block_sum(float s, float* red4) {
  int tid = threadIdx.x;
  for (int off = 32; off; off >>= 1) s += __shfl_down(s, off, 64);
  if ((tid & 63) == 0) red4[tid >> 6] = s;
  __syncthreads();
  return red4[0] + red4[1] + red4[2] + red4[3];
}

static __device__ inline float row_dot_f32(const float* __restrict__ a,
                                           const float* __restrict__ b,
                                           float* red4) {
  const float4* ap = (const float4*)a;
  const float4* bp = (const float4*)b;
  float s = 0.f;
  for (int j = threadIdx.x; j < NN / 4; j += 256) {
    float4 x = ap[j], y = bp[j];
    s += x.x * y.x + x.y * y.y + x.z * y.z + x.w * y.w;
  }
  return block_sum(s, red4);
}

// ---------------------------------------------------------------------------
// topk loaders: fill f[48] with this row's values (one wave, 48 vals/lane).
static __device__ inline void load48_bf(const unsigned short* __restrict__ b0,
                                        int parts, int row, int lane,
                                        float* f) {
  const uint4* r0 = (const uint4*)(b0 + (size_t)row * NN);
#pragma unroll
  for (int j = 0; j < 6; ++j) {
    uint4 q = r0[lane + j * 64];
    unsigned uu[4] = {q.x, q.y, q.z, q.w};
#pragma unroll
    for (int e = 0; e < 4; ++e) {
      f[j * 8 + e * 2] = __uint_as_float(uu[e] << 16);
      f[j * 8 + e * 2 + 1] = __uint_as_float(uu[e] & 0xffff0000u);
    }
  }
  for (int p = 1; p < parts; ++p) {
    const uint4* rp = (const uint4*)(b0 + (size_t)p * NN * NN + (size_t)row * NN);
#pragma unroll
    for (int j = 0; j < 6; ++j) {
      uint4 q = rp[lane + j * 64];
      unsigned uu[4] = {q.x, q.y, q.z, q.w};
#pragma unroll
      for (int e = 0; e < 4; ++e) {
        f[j * 8 + e * 2] += __uint_as_float(uu[e] << 16);
        f[j * 8 + e * 2 + 1] += __uint_as_float(uu[e] & 0xffff0000u);
      }
    }
  }
}

static __device__ inline void load48_f32(const float* __restrict__ A, int row,
                                         int lane, float* f) {
  const float4* r0 = (const float4*)(A + (size_t)row * NN);
#pragma unroll
  for (int j = 0; j < 12; ++j) {
    float4 a = r0[lane + j * 64];
    f[j * 4 + 0] = a.x; f[j * 4 + 1] = a.y;
    f[j * 4 + 2] = a.z; f[j * 4 + 3] = a.w;
  }
}

// ---------------------------------------------------------------------------
// select top-64 of the wave's 64x48 values. Radix on bits [30..16] resolved
// TWO bits per step (counts are monotone c3<=c2<=c1, so "largest 2-bit
// pattern with count>=64" == two greedy single-bit steps) with butterfly
// shfl_xor reduces (all lanes end with the total -> no broadcast). Compact
// (idx*DD, val*scale) into out arrays (128 slots; LDS or global).
static __device__ void select_compact(const float* f, int lane, float descale,
                                      int bf, int* __restrict__ outCnt,
                                      int* __restrict__ outIdx,
                                      float* __restrict__ outVal) {
  unsigned bor = 0, band = 0xffffffffu;
#pragma unroll
  for (int r = 0; r < 48; ++r) {
    unsigned k = __float_as_uint(f[r]);
    bor |= k; band &= k;
  }
  for (int off = 32; off; off >>= 1) {
    bor |= (unsigned)__shfl_xor((int)bor, off, 64);
    band &= (unsigned)__shfl_xor((int)band, off, 64);
  }
  unsigned diff = bor ^ band;
  int hi = diff ? (31 - __clz(diff)) : 16;
  if (hi < 16) hi = 16;
  if (hi > 30) hi = 30;
  unsigned t = band & ~((2u << hi) - 1u);

  int b = hi;
  while (b >= 17) {
    unsigned base = 1u << (b - 1);
    unsigned cand1 = t | base;
    unsigned cand2 = t | (base << 1);
    unsigned cand3 = cand2 | base;
    int c1 = 0, c2 = 0, c3 = 0;
#pragma unroll
    for (int r = 0; r < 48; ++r) {
      unsigned k = __float_as_uint(f[r]);
      c1 += (k >= cand1) ? 1 : 0;
      c2 += (k >= cand2) ? 1 : 0;
      c3 += (k >= cand3) ? 1 : 0;
    }
    for (int off = 32; off; off >>= 1) {
      c1 += __shfl_xor(c1, off, 64);
      c2 += __shfl_xor(c2, off, 64);
      c3 += __shfl_xor(c3, off, 64);
    }
    if (c3 >= 64) t = cand3;
    else if (c2 >= 64) t = cand2;
    else if (c1 >= 64) t = cand1;
    b -= 2;
  }
  if (b == 16) {
    unsigned cand = t | (1u << 16);
    int c = 0;
#pragma unroll
    for (int r = 0; r < 48; ++r) c += (__float_as_uint(f[r]) >= cand) ? 1 : 0;
    for (int off = 32; off; off >>= 1) c += __shfl_xor(c, off, 64);
    if (c >= 64) t = cand;
  }

  int basec = 0;
#pragma unroll
  for (int r = 0; r < 48; ++r) {
    bool keep = __float_as_uint(f[r]) >= t;
    unsigned long long m = __ballot(keep);
    if (keep) {
      int pos = basec + __popcll(m & ((1ull << lane) - 1ull));
      if (pos < 128) {
        int col = bf ? ((r >> 3) * 512 + lane * 8 + (r & 7))
                     : ((r >> 2) * 256 + lane * 4 + (r & 3));
        outIdx[pos] = col << 7;  // pre-scaled by DD for gather addressing
        outVal[pos] = f[r] * descale;
      }
    }
    basec += __popcll(m);
  }
  if (lane == 0) *outCnt = basec < 128 ? basec : 128;
}

// ---------------------------------------------------------------------------
// prep: A -> fp8 PACKED (straight + transposed, x2^19) + fused y1/s1 matvec
// partials. blocks [0,2304): 48x48 tiles of 64x64; blocks [2304,2688):
// concat uemb/iemb -> allE.
__global__ __launch_bounds__(256) void prep(
    const float* __restrict__ A, const float* __restrict__ vu,
    const float* __restrict__ vv, unsigned char* __restrict__ Af8,
    unsigned char* __restrict__ Atf8, float* __restrict__ y1,
    float* __restrict__ s1, const float* __restrict__ uemb,
    const float* __restrict__ iemb, float* __restrict__ allE) {
  __shared__ float sh[64 * 65 + 512];
  const int bid = blockIdx.x;
  const int t = threadIdx.x;
  if (bid >= 2304) {
    int idx = (bid - 2304) * 256 + t;
    int e = idx * 4;
    float4 v = (e < NU * DD) ? *(const float4*)(uemb + e)
                             : *(const float4*)(iemb + (e - NU * DD));
    *(float4*)(allE + e) = v;
    return;
  }
  const int bx = (bid % 48) * 64, by = (bid / 48) * 64;
  const int rr = t >> 4;
  const int c4 = (t & 15) * 4;
  for (int it = 0; it < 4; ++it) {
    int r = rr + it * 16;
    float4 val = *(const float4*)(A + (size_t)(by + r) * NN + bx + c4);
    sh[r * 65 + c4] = val.x; sh[r * 65 + c4 + 1] = val.y;
    sh[r * 65 + c4 + 2] = val.z; sh[r * 65 + c4 + 3] = val.w;
  }
  __syncthreads();
  {
    int row = t >> 2, ch = t & 3;
    const float* sp = &sh[row * 65 + ch * 16];
    uint4 w;
    w.x = pk4_f8(sp[0] * SCALE_A, sp[1] * SCALE_A, sp[2] * SCALE_A,
                 sp[3] * SCALE_A);
    w.y = pk4_f8(sp[4] * SCALE_A, sp[5] * SCALE_A, sp[6] * SCALE_A,
                 sp[7] * SCALE_A);
    w.z = pk4_f8(sp[8] * SCALE_A, sp[9] * SCALE_A, sp[10] * SCALE_A,
                 sp[11] * SCALE_A);
    w.w = pk4_f8(sp[12] * SCALE_A, sp[13] * SCALE_A, sp[14] * SCALE_A,
                 sp[15] * SCALE_A);
    *(uint4*)(Af8 + (size_t)(bx >> 6) * KBLK + (size_t)(by + row) * 64 +
              ch * 16) = w;
  }
  {
    int c = t >> 2, ch = t & 3;
    float v[16];
#pragma unroll
    for (int e = 0; e < 16; ++e) v[e] = sh[(ch * 16 + e) * 65 + c];
    uint4 w;
    w.x = pk4_f8(v[0] * SCALE_A, v[1] * SCALE_A, v[2] * SCALE_A,
                 v[3] * SCALE_A);
    w.y = pk4_f8(v[4] * SCALE_A, v[5] * SCALE_A, v[6] * SCALE_A,
                 v[7] * SCALE_A);
    w.z = pk4_f8(v[8] * SCALE_A, v[9] * SCALE_A, v[10] * SCALE_A,
                 v[11] * SCALE_A);
    w.w = pk4_f8(v[12] * SCALE_A, v[13] * SCALE_A, v[14] * SCALE_A,
                 v[15] * SCALE_A);
    *(uint4*)(Atf8 + (size_t)(by >> 6) * KBLK + (size_t)(bx + c) * 64 +
              ch * 16) = w;
  }
  const int q = t >> 6;
  const int l = t & 63;
  float sy = 0.f, ss_ = 0.f;
  for (int i = 0; i < 16; ++i) {
    int c = q * 16 + i;
    sy += sh[l * 65 + c] * vv[bx + c];
    ss_ += vu[by + c] * sh[c * 65 + l];
  }
  float* red = sh + 64 * 65;
  red[q * 64 + l] = sy;
  red[256 + q * 64 + l] = ss_;
  __syncthreads();
  if (t < 64) {
    float v4 = red[t] + red[64 + t] + red[128 + t] + red[192 + t];
    atomAddF(&y1[by + t], v4);
  } else if (t < 128) {
    int cc = t - 64;
    float v4 = red[256 + cc] + red[256 + 64 + cc] + red[256 + 128 + cc] +
               red[256 + 192 + cc];
    atomAddF(&s1[bx + cc], v4);
  }
}

// ---------------------------------------------------------------------------
// gemm_f8 v10: 192x192 tile, 8 waves (512 thr) with IN-BLOCK K-SPLIT.
// v9 post-mortem: grid 256 x 4 waves = 1 wave/SIMD -> zero TLP; every
// latency term (LDS latency, barrier skew, staging) sat on the critical
// path (~1650 cy/step vs 144 cy of MFMA). v10: waves split into two
// K-groups (kp = w>>2); group kp owns tiles kt = 2i+kp with its OWN
// 3-buffer pipeline (2 x 3 x 24 KB = 144 KB LDS). Block barrier keeps the
// two symmetric groups in lockstep; v9's race proof holds per group.
// 2 waves/SIMD -> co-resident wave fills all stall gaps. Epilogue: kp=1
// dumps its 9 accs into the dead LDS buffers (exactly 144 KB), one
// __syncthreads, kp=0 adds and writes C.
static __device__ inline i32x8 ldfragL(const char* p) {
  i32x4 lo = *(const i32x4*)p;
  i32x4 hi = *(const i32x4*)(p + 1024);
  return (i32x8){lo.x, lo.y, lo.z, lo.w, hi.x, hi.y, hi.z, hi.w};
}

__global__ __launch_bounds__(512) void gemm_f8(
    const unsigned char* __restrict__ Ag,
    const unsigned char* __restrict__ Btg,
    unsigned short* __restrict__ Cg) {
  __shared__ char smem[2][3][24576];  // [kp][slot] -> 144 KiB
  // grid 256 = 16x16 panels of 192; each XCD owns 2 column panels (B panel
  // working set 1.15 MB -> L2-resident for the whole GEMM).
  const int wg = blockIdx.x;
  const int xcd = wg & 7;
  const int idx = wg >> 3;             // 0..31
  const int bxi = xcd * 2 + (idx & 1); // column panel 0..15
  const int byi = idx >> 1;            // row panel    0..15
  const int rowBase = byi * 192, colBase = bxi * 192;

  const int t = threadIdx.x;
  const int w = t >> 6, l = t & 63;
  const int kp = w >> 2;               // K-group 0/1
  const int wq = w & 3;                // wave id within group
  const int wr = wq >> 1, wc = wq & 1;
  const int r32 = l & 31, hh = l >> 5;

  f32x16 acc[3][3];
#pragma unroll
  for (int i = 0; i < 3; ++i)
#pragma unroll
    for (int j = 0; j < 3; ++j)
#pragma unroll
      for (int e = 0; e < 16; ++e) acc[i][j][e] = 0.f;

  const unsigned char* aT = Ag + (size_t)rowBase * 64;
  const unsigned char* bT = Btg + (size_t)colBase * 64;
  const int laneOff = r32 * 64 + hh * 32;

  // 24 chunks x 1KB per buffer: q<12 = A (6 row-subtiles x 2 halves),
  // q>=12 = B. Chunk (s,h) at lane slot l*16 holds global bytes
  // {row = s*32 + (l&31), byte = (l>>5)*32 + h*16} — the exact MFMA
  // operand bytes for lane l (verified mapping from v7/v9). Staged by the
  // 4 waves of the OWNING group (6 chunks per wave -> vmcnt granularity 6).
#define STAGE(kt, b)                                                        \
  {                                                                         \
    const size_t kOff = (size_t)(kt) * KBLK;                                \
    _Pragma("unroll") for (int r_ = 0; r_ < 6; ++r_) {                      \
      int q_ = r_ * 4 + wq;                                                 \
      int qq_ = q_ < 12 ? q_ : q_ - 12;                                     \
      int s_ = qq_ >> 1, h_ = qq_ & 1;                                      \
      const unsigned char* g_ = ((q_ < 12) ? aT : bT) + kOff +              \
                                (size_t)(s_ * 32) * 64 + laneOff + h_ * 16; \
      __builtin_amdgcn_global_load_lds(                                     \
          (const __attribute__((address_space(1))) unsigned*)g_,            \
          (__attribute__((address_space(3))) unsigned*)(smem[kp][b] +       \
                                                        q_ * 1024),         \
          16, 0, 0);                                                        \
    }                                                                       \
  }

  const int ni = 24;  // tiles per group (48 total, kt = 2i+kp)
  STAGE(kp, 0);
  STAGE(2 + kp, 1);
  for (int i = 0; i < ni; ++i) {
    // wait own stage-i loads (6); stage i+1 (6) stays in flight
    if (i < ni - 1) {
      asm volatile("s_waitcnt vmcnt(6)" ::: "memory");
    } else {
      asm volatile("s_waitcnt vmcnt(0)" ::: "memory");
    }
    __builtin_amdgcn_s_barrier();
    __builtin_amdgcn_sched_barrier(0);
    const char* sb = smem[kp][i % 3];
    i32x8 af[3], bfr[3];
#pragma unroll
    for (int ii = 0; ii < 3; ++ii)
      af[ii] = ldfragL(sb + (wr * 3 + ii) * 2048 + l * 16);
#pragma unroll
    for (int j = 0; j < 3; ++j)
      bfr[j] = ldfragL(sb + 12288 + (wc * 3 + j) * 2048 + l * 16);
    if (i + 2 < ni) STAGE(2 * (i + 2) + kp, (i + 2) % 3);
    __builtin_amdgcn_s_setprio(1);
#pragma unroll
    for (int ii = 0; ii < 3; ++ii)
#pragma unroll
      for (int j = 0; j < 3; ++j)
        acc[ii][j] = __builtin_amdgcn_mfma_scale_f32_32x32x64_f8f6f4(
            af[ii], bfr[j], acc[ii][j], 0, 0, 0, 127, 0, 127);
    __builtin_amdgcn_s_setprio(0);
    __builtin_amdgcn_sched_barrier(0);
  }
#undef STAGE

  // merge kp=1 accs into kp=0 via the (now dead) LDS buffers: 4 waves x
  // 9 tiles x 64 lanes x 16 floats = 147456 B = exactly the smem block.
  float* mbase = (float*)&smem[0][0][0];
  if (kp == 1) {
    float* dst = mbase + (size_t)wq * 9216;
#pragma unroll
    for (int i = 0; i < 3; ++i)
#pragma unroll
      for (int j = 0; j < 3; ++j) {
        float* p = dst + (i * 3 + j) * 1024 + l * 16;
#pragma unroll
        for (int e = 0; e < 16; ++e) p[e] = acc[i][j][e];
      }
  }
  __syncthreads();
  if (kp == 0) {
    const float* src = mbase + (size_t)wq * 9216;
#pragma unroll
    for (int i = 0; i < 3; ++i)
#pragma unroll
      for (int j = 0; j < 3; ++j) {
        const float* p = src + (i * 3 + j) * 1024 + l * 16;
#pragma unroll
        for (int e = 0; e < 16; ++e) acc[i][j][e] += p[e];
      }
    // C/D 32x32 layout: col = lane&31, row = (reg&3)+8*(reg>>2)+4*(lane>>5)
#pragma unroll
    for (int i = 0; i < 3; ++i) {
      int rb = rowBase + wr * 96 + i * 32 + 4 * hh;
#pragma unroll
      for (int j = 0; j < 3; ++j) {
        int cc = colBase + wc * 96 + j * 32 + r32;
#pragma unroll
        for (int reg = 0; reg < 16; ++reg) {
          int rr = rb + (reg & 3) + 8 * (reg >> 2);
          Cg[(size_t)rr * NN + cc] = bf16bits(acc[i][j][reg]);
        }
      }
    }
  }
}

// ---------------------------------------------------------------------------
// post1: [0,768)     topk(A2 bf16) + packed fp8 cast -> A2f8
//        [768,1536)  tvec = A.y1 (one wave per row)
__global__ __launch_bounds__(256) void post1(
    const unsigned short* __restrict__ C, int parts,
    const float* __restrict__ A, const float* __restrict__ y1,
    unsigned char* __restrict__ A2f8, int* __restrict__ cnts1,
    int* __restrict__ tIdx1, float* __restrict__ tVal1,
    float* __restrict__ tvec) {
  const int bid = blockIdx.x;
  const int t = threadIdx.x;
  if (bid < 768) {
    int row = bid * 4 + (t >> 6);
    int lane = t & 63;
    float f[48];
    load48_bf(C, parts, row, lane, f);
    // fused packed fp8 cast: f[j*8+e] = col k0+e, k0=(j*64+lane)*8
#pragma unroll
    for (int j = 0; j < 6; ++j) {
      uint2 w;
      w.x = pk4_f8(f[j * 8 + 0] * F8SCALE2, f[j * 8 + 1] * F8SCALE2,
                   f[j * 8 + 2] * F8SCALE2, f[j * 8 + 3] * F8SCALE2);
      w.y = pk4_f8(f[j * 8 + 4] * F8SCALE2, f[j * 8 + 5] * F8SCALE2,
                   f[j * 8 + 6] * F8SCALE2, f[j * 8 + 7] * F8SCALE2);
      size_t addr = (size_t)(j * 8 + (lane >> 3)) * KBLK +
                    (size_t)row * 64 + (lane & 7) * 8;
      *(uint2*)(A2f8 + addr) = w;
    }
    select_compact(f, lane, DESCALE38, 1, &cnts1[row],
                   tIdx1 + (size_t)row * 128, tVal1 + (size_t)row * 128);
  } else {
    int row = (bid - 768) * 4 + (t >> 6);
    int lane = t & 63;
    const float4* rp = (const float4*)(A + (size_t)row * NN);
    const float4* yp = (const float4*)y1;
    float s = 0.f;
#pragma unroll
    for (int j = 0; j < 12; ++j) {
      float4 a = rp[lane + j * 64];
      float4 y = yp[lane + j * 64];
      s += a.x * y.x + a.y * y.y + a.z * y.z + a.w * y.w;
    }
    for (int off = 32; off; off >>= 1) s += __shfl_down(s, off, 64);
    if (lane == 0) tvec[row] = s;
  }
}

// ---------------------------------------------------------------------------
// sel02: phase-homogeneous select kernel (one select per wave, dense waves).
//   bid < 1536, even: layer-2 lists from C (A3 bf16) -> global
//   bid < 1536, odd:  layer-0 lists from A (fp32)    -> global
//   bid == 1536:      post2 fold (w0..w3 -> wacc)
__global__ __launch_bounds__(256) void sel02(
    const unsigned short* __restrict__ C, int parts,
    const float* __restrict__ A, int* __restrict__ cnt0,
    int* __restrict__ idx0, float* __restrict__ val0,
    int* __restrict__ cnt2, int* __restrict__ idx2,
    float* __restrict__ val2, const float* __restrict__ vu,
    const float* __restrict__ vv, const float* __restrict__ y1,
    const float* __restrict__ s1, const float* __restrict__ tvec,
    float* __restrict__ wacc) {
  __shared__ float red4[4];
  const int bid = blockIdx.x;
  const int t = threadIdx.x;
  if (bid == 1536) {
    float w0 = row_dot_f32(vu, vv, red4);  __syncthreads();
    float w1 = row_dot_f32(vu, y1, red4);  __syncthreads();
    float w2 = row_dot_f32(s1, y1, red4);  __syncthreads();
    float w3 = row_dot_f32(s1, tvec, red4);
    if (t == 0) { wacc[0] = w0; wacc[1] = w1; wacc[2] = w2; wacc[3] = w3; }
    return;
  }
  const int w = t >> 6, lane = t & 63;
  const int row = (bid >> 1) * 4 + w;
  float f[48];
  if ((bid & 1) == 0) {
    load48_bf(C, parts, row, lane, f);
    select_compact(f, lane, DESCALE38, 1, &cnt2[row],
                   idx2 + (size_t)row * 128, val2 + (size_t)row * 128);
  } else {
    load48_f32(A, row, lane, f);
    select_compact(f, lane, 1.0f, 0, &cnt0[row],
                   idx0 + (size_t)row * 128, val0 + (size_t)row * 128);
  }
}

// ---------------------------------------------------------------------------
// gather_light: pure gather, one wave per row (768 blocks x 256 thr).
__global__ __launch_bounds__(256) void gather_light(
    const float* __restrict__ allE, const float* __restrict__ uemb0,
    const float* __restrict__ iemb0, const float* __restrict__ wacc,
    const int* __restrict__ cnt0, const int* __restrict__ idx0,
    const float* __restrict__ val0, const int* __restrict__ cnts1,
    const int* __restrict__ tIdx1, const float* __restrict__ tVal1,
    const int* __restrict__ cnt2, const int* __restrict__ idx2,
    const float* __restrict__ val2, float* __restrict__ lightOut) {
  __shared__ int li[4][384];
  __shared__ float lv[4][384];
  const int t = threadIdx.x;
  const int w = t >> 6, lane = t & 63;
  const int row = blockIdx.x * 4 + w;

  float w0 = wacc[0], w1 = wacc[1], w2 = wacc[2], w3 = wacc[3];
  float ss = w0 + w1 + w2 + w3;
  w0 /= ss; w1 /= ss; w2 /= ss; w3 /= ss;
  float m = fmaxf(fmaxf(w0, w1), fmaxf(w2, w3));
  float ex0 = expf(w0 - m), ex1 = expf(w1 - m), ex2 = expf(w2 - m),
        ex3 = expf(w3 - m);
  float se = ex0 + ex1 + ex2 + ex3;
  float aw0 = ex0 / se, aw1 = ex1 / se, aw2 = ex2 / se, aw3 = ex3 / se;
  float aw4 = GAMMA_F * (aw1 + aw2 + aw3);

  const int c0 = cnt0[row], c1 = cnts1[row], c2 = cnt2[row];
  const int p0 = (c0 + 7) & ~7, p1 = (c1 + 7) & ~7, p2 = (c2 + 7) & ~7;
  int* Li = li[w];
  float* Lv = lv[w];
  const size_t rb = (size_t)row * 128;
  for (int k = lane; k < p0; k += 64) {
    bool in = k < c0;
    Li[k] = in ? idx0[rb + k] : 0;
    Lv[k] = in ? aw1 * val0[rb + k] : 0.f;
  }
  for (int k = lane; k < p1; k += 64) {
    bool in = k < c1;
    Li[p0 + k] = in ? tIdx1[rb + k] : 0;
    Lv[p0 + k] = in ? aw2 * tVal1[rb + k] : 0.f;
  }
  for (int k = lane; k < p2; k += 64) {
    bool in = k < c2;
    Li[p0 + p1 + k] = in ? idx2[rb + k] : 0;
    Lv[p0 + p1 + k] = in ? aw3 * val2[rb + k] : 0.f;
  }
  // same-wave produce->consume through LDS: compiler orders via lgkmcnt.

  const int ct = p0 + p1 + p2;
  const float2* E2 = (const float2*)allE;
  float ax = 0.f, ay = 0.f, bx_ = 0.f, by_ = 0.f;
  for (int k = 0; k < ct; k += 8) {
    int i0 = Li[k + 0], i1 = Li[k + 1], i2 = Li[k + 2], i3 = Li[k + 3];
    int i4 = Li[k + 4], i5 = Li[k + 5], i6 = Li[k + 6], i7 = Li[k + 7];
    float v0 = Lv[k + 0], v1 = Lv[k + 1], v2 = Lv[k + 2], v3 = Lv[k + 3];
    float v4 = Lv[k + 4], v5 = Lv[k + 5], v6 = Lv[k + 6], v7 = Lv[k + 7];
    float2 g0 = E2[(i0 >> 1) + lane];
    float2 g1 = E2[(i1 >> 1) + lane];
    float2 g2 = E2[(i2 >> 1) + lane];
    float2 g3 = E2[(i3 >> 1) + lane];
    float2 g4 = E2[(i4 >> 1) + lane];
    float2 g5 = E2[(i5 >> 1) + lane];
    float2 g6 = E2[(i6 >> 1) + lane];
    float2 g7 = E2[(i7 >> 1) + lane];
    ax += v0 * g0.x; ay += v0 * g0.y;
    bx_ += v1 * g1.x; by_ += v1 * g1.y;
    ax += v2 * g2.x; ay += v2 * g2.y;
    bx_ += v3 * g3.x; by_ += v3 * g3.y;
    ax += v4 * g4.x; ay += v4 * g4.y;
    bx_ += v5 * g5.x; by_ += v5 * g5.y;
    ax += v6 * g6.x; ay += v6 * g6.y;
    bx_ += v7 * g7.x; by_ += v7 * g7.y;
  }
  float2 sE = E2[((size_t)row << 6) + lane];
  float2 e0 = (row < NU)
                  ? ((const float2*)uemb0)[(size_t)row * 64 + lane]
                  : ((const float2*)iemb0)[(size_t)(row - NU) * 64 + lane];
  float ox = (ax + bx_) + aw0 * sE.x + aw4 * e0.x;
  float oy = (ay + by_) + aw0 * sE.y + aw4 * e0.y;
  float2 o; o.x = ox; o.y = oy;
  ((float2*)lightOut)[(size_t)row * 64 + lane] = o;
}

__global__ __launch_bounds__(256) void out_dot(const int* __restrict__ users,
                                               const int* __restrict__ items,
                                               const float* __restrict__ lightOut,
                                               float* __restrict__ out) {
  int b = blockIdx.x * 4 + (threadIdx.x >> 6);
  int lane = threadIdx.x & 63;
  const float* up = lightOut + (size_t)users[b] * DD;
  const float* ip = lightOut + (size_t)(NU + items[b]) * DD;
  float s = up[lane] * ip[lane] + up[lane + 64] * ip[lane + 64];
  for (int off = 32; off; off >>= 1) s += __shfl_down(s, off, 64);
  if (lane == 0) out[b] = s;
}

// ---------------------------------------------------------------------------
extern "C" void kernel_launch(void* const* d_in, const int* in_sizes, int n_in,
                              void* d_out, int out_size, void* d_ws,
                              size_t ws_size, hipStream_t stream) {
  const int* users = (const int*)d_in[0];
  const int* items = (const int*)d_in[1];
  const float* A = (const float*)d_in[2];
  const float* uemb = (const float*)d_in[3];
  const float* iemb = (const float*)d_in[4];
  const float* uemb0 = (const float*)d_in[5];
  const float* iemb0 = (const float*)d_in[6];
  const float* vu = (const float*)d_in[7];
  const float* vv = (const float*)d_in[8];
  float* out = (float*)d_out;

  char* ws = (char*)d_ws;
  size_t off = 0;
  auto alloc = [&](size_t bytes) -> void* {
    void* p = ws + off;
    off += (bytes + 255) & ~(size_t)255;
    return p;
  };
  unsigned char* Af8 = (unsigned char*)alloc((size_t)NN * NN);
  unsigned char* Atf8 = (unsigned char*)alloc((size_t)NN * NN);
  unsigned char* A2f8 = (unsigned char*)alloc((size_t)NN * NN);
  float* y1 = (float*)alloc((size_t)NN * 4);   // contiguous with s1
  float* s1 = (float*)alloc((size_t)NN * 4);
  float* tvec = (float*)alloc((size_t)NN * 4);
  float* wacc = (float*)alloc(256);
  int* cnts1 = (int*)alloc((size_t)NN * 4);
  int* tIdx1 = (int*)alloc((size_t)NN * 128 * 4);
  float* tVal1 = (float*)alloc((size_t)NN * 128 * 4);
  float* lightOut = (float*)alloc((size_t)NN * DD * 4);
  int* cnt0 = (int*)alloc((size_t)NN * 4);
  int* cnt2 = (int*)alloc((size_t)NN * 4);
  float* allE = (float*)alloc((size_t)NN * DD * 4);  // dedicated (no alias)

  // layer-0/2 lists (4 x 1.5 MB) alias Atf8 (9.4 MB): Atf8 is dead after
  // gemm#2 (step 5); sel02 (step 6) writes, gather (step 8) reads.
  const size_t LSTB = (size_t)NN * 128 * 4;
  int* idx0 = (int*)(Atf8);
  float* val0 = (float*)(Atf8 + LSTB);
  int* idx2 = (int*)(Atf8 + 2 * LSTB);
  float* val2 = (float*)(Atf8 + 3 * LSTB);

  // single-part bf16 C
  unsigned short* C = (unsigned short*)alloc((size_t)NN * NN * 2);

  // 1) zero y1/s1 (contiguous 2*NN floats)
  hipMemsetAsync(y1, 0, (size_t)2 * NN * 4, stream);
  // 2) prep: A -> packed fp8 (straight+transposed) + y1/s1 | emb concat
  prep<<<2688, 256, 0, stream>>>(A, vu, vv, Af8, Atf8, y1, s1, uemb, iemb,
                                 allE);
  // 3) A2 = A*A (192-tile, 8-wave in-block K-split, 2 waves/SIMD)
  gemm_f8<<<256, 512, 0, stream>>>(Af8, Atf8, C);
  // 4) post1: topk(A2)+packed fp8 cast | tvec = A.y1
  post1<<<1536, 256, 0, stream>>>(C, 1, A, y1, A2f8, cnts1, tIdx1, tVal1,
                                  tvec);
  // 5) A3 = A2*A (overwrite C)
  gemm_f8<<<256, 512, 0, stream>>>(A2f8, Atf8, C);
  // 6) sel02: layer-0 (A) + layer-2 (A3) top-64 lists | post2 fold (bid 1536)
  sel02<<<1537, 256, 0, stream>>>(C, 1, A, cnt0, idx0, val0, cnt2, idx2,
                                  val2, vu, vv, y1, s1, tvec, wacc);
  // 7) gather_light: pure float2 gather, one wave per row
  gather_light<<<768, 256, 0, stream>>>(allE, uemb0, iemb0, wacc, cnt0, idx0,
                                        val0, cnts1, tIdx1, tVal1, cnt2, idx2,
                                        val2, lightOut);
  // 8) gather dots
  out_dot<<<BB / 4, 256, 0, stream>>>(users, items, lightOut, out);
}

// Round 10
// 238.144 us; speedup vs baseline: 1.0086x; 1.0086x over previous
//
#include <hip/hip_runtime.h>
#include <hip/hip_fp8.h>
#include <math.h>

#define NN 3072
#define NU 1024
#define NI 2048
#define DD 128
#define BB 8192
#define GAMMA_F 0.2f

#define SCALE_A 524288.0f                // 2^19
#define F8SCALE2 1.9073486328125e-06f    // 2^-19  (C*2^38 -> A2*2^19 for fp8)
#define DESCALE38 3.637978807091713e-12f // 2^-38  (C -> true A^k values)

// packed fp8 layout: [k/64][row][k%64]; one k-block = NN rows x 64 B
#define KBLK ((size_t)NN * 64)

typedef __attribute__((ext_vector_type(4))) float f32x4;
typedef __attribute__((ext_vector_type(16))) float f32x16;
typedef __attribute__((ext_vector_type(4))) int i32x4;
typedef __attribute__((ext_vector_type(8))) int i32x8;

static __device__ inline unsigned short bf16bits(float x) {
  union { unsigned u; float f; } cv;
  cv.f = x;
  unsigned r = cv.u + 0x7fff + ((cv.u >> 16) & 1);  // RNE
  return (unsigned short)(r >> 16);
}

// pack 4 floats -> 4 fp8 e4m3 (OCP) bytes
static __device__ inline unsigned pk4_f8(float a, float b, float c, float d) {
#if defined(__has_builtin)
#if __has_builtin(__builtin_amdgcn_cvt_pk_fp8_f32)
  int p = __builtin_amdgcn_cvt_pk_fp8_f32(a, b, 0, false);
  p = __builtin_amdgcn_cvt_pk_fp8_f32(c, d, p, true);
  return (unsigned)p;
#else
  return (unsigned)__hip_fp8_e4m3(a).__x | ((unsigned)__hip_fp8_e4m3(b).__x << 8) |
         ((unsigned)__hip_fp8_e4m3(c).__x << 16) |
         ((unsigned)__hip_fp8_e4m3(d).__x << 24);
#endif
#else
  return (unsigned)__hip_fp8_e4m3(a).__x | ((unsigned)__hip_fp8_e4m3(b).__x << 8) |
         ((unsigned)__hip_fp8_e4m3(c).__x << 16) |
         ((unsigned)__hip_fp8_e4m3(d).__x << 24);
#endif
}

static __device__ inline void atomAddF(float* p, float v) {
#if defined(__has_builtin)
#if __has_builtin(__builtin_amdgcn_global_atomic_fadd_f32)
  __builtin_amdgcn_global_atomic_fadd_f32(
      (__attribute__((address_space(1))) float*)p, v);
#else
  unsafeAtomicAdd(p, v);
#endif
#else
  unsafeAtomicAdd(p, v);
#endif
}

static __device__ inline float block_sum(float s, float* red4) {
  int tid = threadIdx.x;
  for (int off = 32; off; off >>= 1) s += __shfl_down(s, off, 64);
  if ((tid & 63) == 0) red4[tid >> 6] = s;
  __syncthreads();
  return red4[0] + red4[1] + red4[2] + red4[3];
}

static __device__ inline float row_dot_f32(const float* __restrict__ a,
                                           const float* __restrict__ b,
                                           float* red4) {
  const float4* ap = (const float4*)a;
  const float4* bp = (const float4*)b;
  float s = 0.f;
  for (int j = threadIdx.x; j < NN / 4; j += 256) {
    float4 x = ap[j], y = bp[j];
    s += x.x * y.x + x.y * y.y + x.z * y.z + x.w * y.w;
  }
  return block_sum(s, red4);
}

// ---------------------------------------------------------------------------
// topk loaders: fill f[48] with this row's values (one wave, 48 vals/lane).
static __device__ inline void load48_bf(const unsigned short* __restrict__ b0,
                                        int parts, int row, int lane,
                                        float* f) {
  const uint4* r0 = (const uint4*)(b0 + (size_t)row * NN);
#pragma unroll
  for (int j = 0; j < 6; ++j) {
    uint4 q = r0[lane + j * 64];
    unsigned uu[4] = {q.x, q.y, q.z, q.w};
#pragma unroll
    for (int e = 0; e < 4; ++e) {
      f[j * 8 + e * 2] = __uint_as_float(uu[e] << 16);
      f[j * 8 + e * 2 + 1] = __uint_as_float(uu[e] & 0xffff0000u);
    }
  }
  for (int p = 1; p < parts; ++p) {
    const uint4* rp = (const uint4*)(b0 + (size_t)p * NN * NN + (size_t)row * NN);
#pragma unroll
    for (int j = 0; j < 6; ++j) {
      uint4 q = rp[lane + j * 64];
      unsigned uu[4] = {q.x, q.y, q.z, q.w};
#pragma unroll
      for (int e = 0; e < 4; ++e) {
        f[j * 8 + e * 2] += __uint_as_float(uu[e] << 16);
        f[j * 8 + e * 2 + 1] += __uint_as_float(uu[e] & 0xffff0000u);
      }
    }
  }
}

static __device__ inline void load48_f32(const float* __restrict__ A, int row,
                                         int lane, float* f) {
  const float4* r0 = (const float4*)(A + (size_t)row * NN);
#pragma unroll
  for (int j = 0; j < 12; ++j) {
    float4 a = r0[lane + j * 64];
    f[j * 4 + 0] = a.x; f[j * 4 + 1] = a.y;
    f[j * 4 + 2] = a.z; f[j * 4 + 3] = a.w;
  }
}

// ---------------------------------------------------------------------------
// select top-64 of the wave's 64x48 values. Radix on bits [30..16] resolved
// TWO bits per step (counts are monotone c3<=c2<=c1, so "largest 2-bit
// pattern with count>=64" == two greedy single-bit steps) with butterfly
// shfl_xor reduces (all lanes end with the total -> no broadcast). Compact
// (idx*DD, val*scale) into out arrays (128 slots; LDS or global).
static __device__ void select_compact(const float* f, int lane, float descale,
                                      int bf, int* __restrict__ outCnt,
                                      int* __restrict__ outIdx,
                                      float* __restrict__ outVal) {
  unsigned bor = 0, band = 0xffffffffu;
#pragma unroll
  for (int r = 0; r < 48; ++r) {
    unsigned k = __float_as_uint(f[r]);
    bor |= k; band &= k;
  }
  for (int off = 32; off; off >>= 1) {
    bor |= (unsigned)__shfl_xor((int)bor, off, 64);
    band &= (unsigned)__shfl_xor((int)band, off, 64);
  }
  unsigned diff = bor ^ band;
  int hi = diff ? (31 - __clz(diff)) : 16;
  if (hi < 16) hi = 16;
  if (hi > 30) hi = 30;
  unsigned t = band & ~((2u << hi) - 1u);

  int b = hi;
  while (b >= 17) {
    unsigned base = 1u << (b - 1);
    unsigned cand1 = t | base;
    unsigned cand2 = t | (base << 1);
    unsigned cand3 = cand2 | base;
    int c1 = 0, c2 = 0, c3 = 0;
#pragma unroll
    for (int r = 0; r < 48; ++r) {
      unsigned k = __float_as_uint(f[r]);
      c1 += (k >= cand1) ? 1 : 0;
      c2 += (k >= cand2) ? 1 : 0;
      c3 += (k >= cand3) ? 1 : 0;
    }
    for (int off = 32; off; off >>= 1) {
      c1 += __shfl_xor(c1, off, 64);
      c2 += __shfl_xor(c2, off, 64);
      c3 += __shfl_xor(c3, off, 64);
    }
    if (c3 >= 64) t = cand3;
    else if (c2 >= 64) t = cand2;
    else if (c1 >= 64) t = cand1;
    b -= 2;
  }
  if (b == 16) {
    unsigned cand = t | (1u << 16);
    int c = 0;
#pragma unroll
    for (int r = 0; r < 48; ++r) c += (__float_as_uint(f[r]) >= cand) ? 1 : 0;
    for (int off = 32; off; off >>= 1) c += __shfl_xor(c, off, 64);
    if (c >= 64) t = cand;
  }

  int basec = 0;
#pragma unroll
  for (int r = 0; r < 48; ++r) {
    bool keep = __float_as_uint(f[r]) >= t;
    unsigned long long m = __ballot(keep);
    if (keep) {
      int pos = basec + __popcll(m & ((1ull << lane) - 1ull));
      if (pos < 128) {
        int col = bf ? ((r >> 3) * 512 + lane * 8 + (r & 7))
                     : ((r >> 2) * 256 + lane * 4 + (r & 3));
        outIdx[pos] = col << 7;  // pre-scaled by DD for gather addressing
        outVal[pos] = f[r] * descale;
      }
    }
    basec += __popcll(m);
  }
  if (lane == 0) *outCnt = basec < 128 ? basec : 128;
}

// ---------------------------------------------------------------------------
// prep: A -> fp8 PACKED (straight + transposed, x2^19) + fused y1/s1 matvec
// partials. blocks [0,2304): 48x48 tiles of 64x64; blocks [2304,2688):
// concat uemb/iemb -> allE.
__global__ __launch_bounds__(256) void prep(
    const float* __restrict__ A, const float* __restrict__ vu,
    const float* __restrict__ vv, unsigned char* __restrict__ Af8,
    unsigned char* __restrict__ Atf8, float* __restrict__ y1,
    float* __restrict__ s1, const float* __restrict__ uemb,
    const float* __restrict__ iemb, float* __restrict__ allE) {
  __shared__ float sh[64 * 65 + 512];
  const int bid = blockIdx.x;
  const int t = threadIdx.x;
  if (bid >= 2304) {
    int idx = (bid - 2304) * 256 + t;
    int e = idx * 4;
    float4 v = (e < NU * DD) ? *(const float4*)(uemb + e)
                             : *(const float4*)(iemb + (e - NU * DD));
    *(float4*)(allE + e) = v;
    return;
  }
  const int bx = (bid % 48) * 64, by = (bid / 48) * 64;
  const int rr = t >> 4;
  const int c4 = (t & 15) * 4;
  for (int it = 0; it < 4; ++it) {
    int r = rr + it * 16;
    float4 val = *(const float4*)(A + (size_t)(by + r) * NN + bx + c4);
    sh[r * 65 + c4] = val.x; sh[r * 65 + c4 + 1] = val.y;
    sh[r * 65 + c4 + 2] = val.z; sh[r * 65 + c4 + 3] = val.w;
  }
  __syncthreads();
  {
    int row = t >> 2, ch = t & 3;
    const float* sp = &sh[row * 65 + ch * 16];
    uint4 w;
    w.x = pk4_f8(sp[0] * SCALE_A, sp[1] * SCALE_A, sp[2] * SCALE_A,
                 sp[3] * SCALE_A);
    w.y = pk4_f8(sp[4] * SCALE_A, sp[5] * SCALE_A, sp[6] * SCALE_A,
                 sp[7] * SCALE_A);
    w.z = pk4_f8(sp[8] * SCALE_A, sp[9] * SCALE_A, sp[10] * SCALE_A,
                 sp[11] * SCALE_A);
    w.w = pk4_f8(sp[12] * SCALE_A, sp[13] * SCALE_A, sp[14] * SCALE_A,
                 sp[15] * SCALE_A);
    *(uint4*)(Af8 + (size_t)(bx >> 6) * KBLK + (size_t)(by + row) * 64 +
              ch * 16) = w;
  }
  {
    int c = t >> 2, ch = t & 3;
    float v[16];
#pragma unroll
    for (int e = 0; e < 16; ++e) v[e] = sh[(ch * 16 + e) * 65 + c];
    uint4 w;
    w.x = pk4_f8(v[0] * SCALE_A, v[1] * SCALE_A, v[2] * SCALE_A,
                 v[3] * SCALE_A);
    w.y = pk4_f8(v[4] * SCALE_A, v[5] * SCALE_A, v[6] * SCALE_A,
                 v[7] * SCALE_A);
    w.z = pk4_f8(v[8] * SCALE_A, v[9] * SCALE_A, v[10] * SCALE_A,
                 v[11] * SCALE_A);
    w.w = pk4_f8(v[12] * SCALE_A, v[13] * SCALE_A, v[14] * SCALE_A,
                 v[15] * SCALE_A);
    *(uint4*)(Atf8 + (size_t)(by >> 6) * KBLK + (size_t)(bx + c) * 64 +
              ch * 16) = w;
  }
  const int q = t >> 6;
  const int l = t & 63;
  float sy = 0.f, ss_ = 0.f;
  for (int i = 0; i < 16; ++i) {
    int c = q * 16 + i;
    sy += sh[l * 65 + c] * vv[bx + c];
    ss_ += vu[by + c] * sh[c * 65 + l];
  }
  float* red = sh + 64 * 65;
  red[q * 64 + l] = sy;
  red[256 + q * 64 + l] = ss_;
  __syncthreads();
  if (t < 64) {
    float v4 = red[t] + red[64 + t] + red[128 + t] + red[192 + t];
    atomAddF(&y1[by + t], v4);
  } else if (t < 128) {
    int cc = t - 64;
    float v4 = red[256 + cc] + red[256 + 64 + cc] + red[256 + 128 + cc] +
               red[256 + 192 + cc];
    atomAddF(&s1[bx + cc], v4);
  }
}

// ---------------------------------------------------------------------------
// gemm_f8 v11: 192x192 tile, 4 waves, K SPLIT ACROSS BLOCKS (grid 512,
// z = K-half). v10 post-mortem: in-block K-split gave 2 waves/SIMD but the
// block-wide barrier PHASE-LOCKED them (symmetric groups hit MFMA and
// barrier together -> no stall interleave). v11: the 2 co-resident waves
// per SIMD come from INDEPENDENT blocks (2 blocks/CU, 72 KB LDS each,
// __launch_bounds__(256,2) caps VGPR at 256) -> unsynchronized pipelines
// genuinely interleave. Output: 2 bf16 partial planes (z), summed by the
// parts=2 readers (numerics identical to rounds 0-6's kParts=2 path).
static __device__ inline i32x8 ldfragL(const char* p) {
  i32x4 lo = *(const i32x4*)p;
  i32x4 hi = *(const i32x4*)(p + 1024);
  return (i32x8){lo.x, lo.y, lo.z, lo.w, hi.x, hi.y, hi.z, hi.w};
}

__global__ __launch_bounds__(256, 2) void gemm_f8(
    const unsigned char* __restrict__ Ag,
    const unsigned char* __restrict__ Btg,
    unsigned short* __restrict__ Cg) {
  __shared__ char smem[3][24576];  // 72 KiB -> 2 blocks/CU
  // grid 512 = 16x16 panels x 2 K-halves. xcd = bid&7: each XCD owns 2
  // column panels (B panel 1.18 MB, L2-resident); both K-halves of a tile
  // land on the same XCD.
  const int wg = blockIdx.x;
  const int xcd = wg & 7;
  const int idx = wg >> 3;             // 0..63
  const int bxi = xcd * 2 + (idx & 1); // column panel 0..15
  const int byi = (idx >> 1) & 15;     // row panel    0..15
  const int z = idx >> 5;              // K-half 0/1
  const int rowBase = byi * 192, colBase = bxi * 192;

  const int t = threadIdx.x;
  const int w = t >> 6, l = t & 63;
  const int wr = w >> 1, wc = w & 1;
  const int r32 = l & 31, hh = l >> 5;

  f32x16 acc[3][3];
#pragma unroll
  for (int i = 0; i < 3; ++i)
#pragma unroll
    for (int j = 0; j < 3; ++j)
#pragma unroll
      for (int e = 0; e < 16; ++e) acc[i][j][e] = 0.f;

  const unsigned char* aT = Ag + (size_t)rowBase * 64;
  const unsigned char* bT = Btg + (size_t)colBase * 64;
  const int laneOff = r32 * 64 + hh * 32;
  const int kt0 = z * 24;  // this block's K-tile range: [kt0, kt0+24)

  // 24 chunks x 1KB per buffer: q<12 = A (6 row-subtiles x 2 halves),
  // q>=12 = B. Chunk (s,h) at lane slot l*16 holds global bytes
  // {row = s*32 + (l&31), byte = (l>>5)*32 + h*16} — the exact MFMA
  // operand bytes for lane l (verified mapping v7/v9).
#define STAGE(kt, b)                                                        \
  {                                                                         \
    const size_t kOff = (size_t)(kt) * KBLK;                                \
    _Pragma("unroll") for (int r_ = 0; r_ < 6; ++r_) {                      \
      int q_ = r_ * 4 + w;                                                  \
      int qq_ = q_ < 12 ? q_ : q_ - 12;                                     \
      int s_ = qq_ >> 1, h_ = qq_ & 1;                                      \
      const unsigned char* g_ = ((q_ < 12) ? aT : bT) + kOff +              \
                                (size_t)(s_ * 32) * 64 + laneOff + h_ * 16; \
      __builtin_amdgcn_global_load_lds(                                     \
          (const __attribute__((address_space(1))) unsigned*)g_,            \
          (__attribute__((address_space(3))) unsigned*)(smem[b] +           \
                                                        q_ * 1024),         \
          16, 0, 0);                                                        \
    }                                                                       \
  }

  const int ni = 24;
  STAGE(kt0, 0);
  STAGE(kt0 + 1, 1);
  for (int i = 0; i < ni; ++i) {
    // wait own stage-i loads (6); stage i+1 (6) stays in flight
    if (i < ni - 1) {
      asm volatile("s_waitcnt vmcnt(6)" ::: "memory");
    } else {
      asm volatile("s_waitcnt vmcnt(0)" ::: "memory");
    }
    __builtin_amdgcn_s_barrier();
    __builtin_amdgcn_sched_barrier(0);
    const char* sb = smem[i % 3];
    i32x8 af[3], bfr[3];
#pragma unroll
    for (int ii = 0; ii < 3; ++ii)
      af[ii] = ldfragL(sb + (wr * 3 + ii) * 2048 + l * 16);
#pragma unroll
    for (int j = 0; j < 3; ++j)
      bfr[j] = ldfragL(sb + 12288 + (wc * 3 + j) * 2048 + l * 16);
    if (i + 2 < ni) STAGE(kt0 + i + 2, (i + 2) % 3);
    __builtin_amdgcn_s_setprio(1);
#pragma unroll
    for (int ii = 0; ii < 3; ++ii)
#pragma unroll
      for (int j = 0; j < 3; ++j)
        acc[ii][j] = __builtin_amdgcn_mfma_scale_f32_32x32x64_f8f6f4(
            af[ii], bfr[j], acc[ii][j], 0, 0, 0, 127, 0, 127);
    __builtin_amdgcn_s_setprio(0);
    __builtin_amdgcn_sched_barrier(0);
  }
#undef STAGE

  // C/D 32x32 layout: col = lane&31, row = (reg&3) + 8*(reg>>2) + 4*(lane>>5)
  unsigned short* Cout = Cg + (size_t)z * NN * NN;
#pragma unroll
  for (int i = 0; i < 3; ++i) {
    int rb = rowBase + wr * 96 + i * 32 + 4 * hh;
#pragma unroll
    for (int j = 0; j < 3; ++j) {
      int cc = colBase + wc * 96 + j * 32 + r32;
#pragma unroll
      for (int reg = 0; reg < 16; ++reg) {
        int rr = rb + (reg & 3) + 8 * (reg >> 2);
        Cout[(size_t)rr * NN + cc] = bf16bits(acc[i][j][reg]);
      }
    }
  }
}

// ---------------------------------------------------------------------------
// post1: [0,768)     topk(A2 bf16 partial-sum) + packed fp8 cast -> A2f8
//        [768,1536)  tvec = A.y1 (one wave per row)
__global__ __launch_bounds__(256) void post1(
    const unsigned short* __restrict__ C, int parts,
    const float* __restrict__ A, const float* __restrict__ y1,
    unsigned char* __restrict__ A2f8, int* __restrict__ cnts1,
    int* __restrict__ tIdx1, float* __restrict__ tVal1,
    float* __restrict__ tvec) {
  const int bid = blockIdx.x;
  const int t = threadIdx.x;
  if (bid < 768) {
    int row = bid * 4 + (t >> 6);
    int lane = t & 63;
    float f[48];
    load48_bf(C, parts, row, lane, f);
    // fused packed fp8 cast: f[j*8+e] = col k0+e, k0=(j*64+lane)*8
#pragma unroll
    for (int j = 0; j < 6; ++j) {
      uint2 w;
      w.x = pk4_f8(f[j * 8 + 0] * F8SCALE2, f[j * 8 + 1] * F8SCALE2,
                   f[j * 8 + 2] * F8SCALE2, f[j * 8 + 3] * F8SCALE2);
      w.y = pk4_f8(f[j * 8 + 4] * F8SCALE2, f[j * 8 + 5] * F8SCALE2,
                   f[j * 8 + 6] * F8SCALE2, f[j * 8 + 7] * F8SCALE2);
      size_t addr = (size_t)(j * 8 + (lane >> 3)) * KBLK +
                    (size_t)row * 64 + (lane & 7) * 8;
      *(uint2*)(A2f8 + addr) = w;
    }
    select_compact(f, lane, DESCALE38, 1, &cnts1[row],
                   tIdx1 + (size_t)row * 128, tVal1 + (size_t)row * 128);
  } else {
    int row = (bid - 768) * 4 + (t >> 6);
    int lane = t & 63;
    const float4* rp = (const float4*)(A + (size_t)row * NN);
    const float4* yp = (const float4*)y1;
    float s = 0.f;
#pragma unroll
    for (int j = 0; j < 12; ++j) {
      float4 a = rp[lane + j * 64];
      float4 y = yp[lane + j * 64];
      s += a.x * y.x + a.y * y.y + a.z * y.z + a.w * y.w;
    }
    for (int off = 32; off; off >>= 1) s += __shfl_down(s, off, 64);
    if (lane == 0) tvec[row] = s;
  }
}

// ---------------------------------------------------------------------------
// sel02: phase-homogeneous select kernel (one select per wave, dense waves).
//   bid < 1536, even: layer-2 lists from C (A3 bf16 partials) -> global
//   bid < 1536, odd:  layer-0 lists from A (fp32)             -> global
//   bid == 1536:      post2 fold (w0..w3 -> wacc)
__global__ __launch_bounds__(256) void sel02(
    const unsigned short* __restrict__ C, int parts,
    const float* __restrict__ A, int* __restrict__ cnt0,
    int* __restrict__ idx0, float* __restrict__ val0,
    int* __restrict__ cnt2, int* __restrict__ idx2,
    float* __restrict__ val2, const float* __restrict__ vu,
    const float* __restrict__ vv, const float* __restrict__ y1,
    const float* __restrict__ s1, const float* __restrict__ tvec,
    float* __restrict__ wacc) {
  __shared__ float red4[4];
  const int bid = blockIdx.x;
  const int t = threadIdx.x;
  if (bid == 1536) {
    float w0 = row_dot_f32(vu, vv, red4);  __syncthreads();
    float w1 = row_dot_f32(vu, y1, red4);  __syncthreads();
    float w2 = row_dot_f32(s1, y1, red4);  __syncthreads();
    float w3 = row_dot_f32(s1, tvec, red4);
    if (t == 0) { wacc[0] = w0; wacc[1] = w1; wacc[2] = w2; wacc[3] = w3; }
    return;
  }
  const int w = t >> 6, lane = t & 63;
  const int row = (bid >> 1) * 4 + w;
  float f[48];
  if ((bid & 1) == 0) {
    load48_bf(C, parts, row, lane, f);
    select_compact(f, lane, DESCALE38, 1, &cnt2[row],
                   idx2 + (size_t)row * 128, val2 + (size_t)row * 128);
  } else {
    load48_f32(A, row, lane, f);
    select_compact(f, lane, 1.0f, 0, &cnt0[row],
                   idx0 + (size_t)row * 128, val0 + (size_t)row * 128);
  }
}

// ---------------------------------------------------------------------------
// gather_light: pure gather, one wave per row (768 blocks x 256 thr).
__global__ __launch_bounds__(256) void gather_light(
    const float* __restrict__ allE, const float* __restrict__ uemb0,
    const float* __restrict__ iemb0, const float* __restrict__ wacc,
    const int* __restrict__ cnt0, const int* __restrict__ idx0,
    const float* __restrict__ val0, const int* __restrict__ cnts1,
    const int* __restrict__ tIdx1, const float* __restrict__ tVal1,
    const int* __restrict__ cnt2, const int* __restrict__ idx2,
    const float* __restrict__ val2, float* __restrict__ lightOut) {
  __shared__ int li[4][384];
  __shared__ float lv[4][384];
  const int t = threadIdx.x;
  const int w = t >> 6, lane = t & 63;
  const int row = blockIdx.x * 4 + w;

  float w0 = wacc[0], w1 = wacc[1], w2 = wacc[2], w3 = wacc[3];
  float ss = w0 + w1 + w2 + w3;
  w0 /= ss; w1 /= ss; w2 /= ss; w3 /= ss;
  float m = fmaxf(fmaxf(w0, w1), fmaxf(w2, w3));
  float ex0 = expf(w0 - m), ex1 = expf(w1 - m), ex2 = expf(w2 - m),
        ex3 = expf(w3 - m);
  float se = ex0 + ex1 + ex2 + ex3;
  float aw0 = ex0 / se, aw1 = ex1 / se, aw2 = ex2 / se, aw3 = ex3 / se;
  float aw4 = GAMMA_F * (aw1 + aw2 + aw3);

  const int c0 = cnt0[row], c1 = cnts1[row], c2 = cnt2[row];
  const int p0 = (c0 + 7) & ~7, p1 = (c1 + 7) & ~7, p2 = (c2 + 7) & ~7;
  int* Li = li[w];
  float* Lv = lv[w];
  const size_t rb = (size_t)row * 128;
  for (int k = lane; k < p0; k += 64) {
    bool in = k < c0;
    Li[k] = in ? idx0[rb + k] : 0;
    Lv[k] = in ? aw1 * val0[rb + k] : 0.f;
  }
  for (int k = lane; k < p1; k += 64) {
    bool in = k < c1;
    Li[p0 + k] = in ? tIdx1[rb + k] : 0;
    Lv[p0 + k] = in ? aw2 * tVal1[rb + k] : 0.f;
  }
  for (int k = lane; k < p2; k += 64) {
    bool in = k < c2;
    Li[p0 + p1 + k] = in ? idx2[rb + k] : 0;
    Lv[p0 + p1 + k] = in ? aw3 * val2[rb + k] : 0.f;
  }
  // same-wave produce->consume through LDS: compiler orders via lgkmcnt.

  const int ct = p0 + p1 + p2;
  const float2* E2 = (const float2*)allE;
  float ax = 0.f, ay = 0.f, bx_ = 0.f, by_ = 0.f;
  for (int k = 0; k < ct; k += 8) {
    int i0 = Li[k + 0], i1 = Li[k + 1], i2 = Li[k + 2], i3 = Li[k + 3];
    int i4 = Li[k + 4], i5 = Li[k + 5], i6 = Li[k + 6], i7 = Li[k + 7];
    float v0 = Lv[k + 0], v1 = Lv[k + 1], v2 = Lv[k + 2], v3 = Lv[k + 3];
    float v4 = Lv[k + 4], v5 = Lv[k + 5], v6 = Lv[k + 6], v7 = Lv[k + 7];
    float2 g0 = E2[(i0 >> 1) + lane];
    float2 g1 = E2[(i1 >> 1) + lane];
    float2 g2 = E2[(i2 >> 1) + lane];
    float2 g3 = E2[(i3 >> 1) + lane];
    float2 g4 = E2[(i4 >> 1) + lane];
    float2 g5 = E2[(i5 >> 1) + lane];
    float2 g6 = E2[(i6 >> 1) + lane];
    float2 g7 = E2[(i7 >> 1) + lane];
    ax += v0 * g0.x; ay += v0 * g0.y;
    bx_ += v1 * g1.x; by_ += v1 * g1.y;
    ax += v2 * g2.x; ay += v2 * g2.y;
    bx_ += v3 * g3.x; by_ += v3 * g3.y;
    ax += v4 * g4.x; ay += v4 * g4.y;
    bx_ += v5 * g5.x; by_ += v5 * g5.y;
    ax += v6 * g6.x; ay += v6 * g6.y;
    bx_ += v7 * g7.x; by_ += v7 * g7.y;
  }
  float2 sE = E2[((size_t)row << 6) + lane];
  float2 e0 = (row < NU)
                  ? ((const float2*)uemb0)[(size_t)row * 64 + lane]
                  : ((const float2*)iemb0)[(size_t)(row - NU) * 64 + lane];
  float ox = (ax + bx_) + aw0 * sE.x + aw4 * e0.x;
  float oy = (ay + by_) + aw0 * sE.y + aw4 * e0.y;
  float2 o; o.x = ox; o.y = oy;
  ((float2*)lightOut)[(size_t)row * 64 + lane] = o;
}

__global__ __launch_bounds__(256) void out_dot(const int* __restrict__ users,
                                               const int* __restrict__ items,
                                               const float* __restrict__ lightOut,
                                               float* __restrict__ out) {
  int b = blockIdx.x * 4 + (threadIdx.x >> 6);
  int lane = threadIdx.x & 63;
  const float* up = lightOut + (size_t)users[b] * DD;
  const float* ip = lightOut + (size_t)(NU + items[b]) * DD;
  float s = up[lane] * ip[lane] + up[lane + 64] * ip[lane + 64];
  for (int off = 32; off; off >>= 1) s += __shfl_down(s, off, 64);
  if (lane == 0) out[b] = s;
}

// ---------------------------------------------------------------------------
extern "C" void kernel_launch(void* const* d_in, const int* in_sizes, int n_in,
                              void* d_out, int out_size, void* d_ws,
                              size_t ws_size, hipStream_t stream) {
  const int* users = (const int*)d_in[0];
  const int* items = (const int*)d_in[1];
  const float* A = (const float*)d_in[2];
  const float* uemb = (const float*)d_in[3];
  const float* iemb = (const float*)d_in[4];
  const float* uemb0 = (const float*)d_in[5];
  const float* iemb0 = (const float*)d_in[6];
  const float* vu = (const float*)d_in[7];
  const float* vv = (const float*)d_in[8];
  float* out = (float*)d_out;

  char* ws = (char*)d_ws;
  size_t off = 0;
  auto alloc = [&](size_t bytes) -> void* {
    void* p = ws + off;
    off += (bytes + 255) & ~(size_t)255;
    return p;
  };
  unsigned char* Af8 = (unsigned char*)alloc((size_t)NN * NN);
  unsigned char* Atf8 = (unsigned char*)alloc((size_t)NN * NN);
  unsigned char* A2f8 = (unsigned char*)alloc((size_t)NN * NN);
  float* y1 = (float*)alloc((size_t)NN * 4);   // contiguous with s1
  float* s1 = (float*)alloc((size_t)NN * 4);
  float* tvec = (float*)alloc((size_t)NN * 4);
  float* wacc = (float*)alloc(256);
  int* cnts1 = (int*)alloc((size_t)NN * 4);
  int* tIdx1 = (int*)alloc((size_t)NN * 128 * 4);
  float* tVal1 = (float*)alloc((size_t)NN * 128 * 4);
  float* lightOut = (float*)alloc((size_t)NN * DD * 4);
  int* cnt0 = (int*)alloc((size_t)NN * 4);
  int* cnt2 = (int*)alloc((size_t)NN * 4);
  float* allE = (float*)alloc((size_t)NN * DD * 4);  // dedicated (no alias)

  // layer-0/2 lists (4 x 1.5 MB) alias Atf8 (9.4 MB): Atf8 is dead after
  // gemm#2 (step 5); sel02 (step 6) writes, gather (step 8) reads.
  const size_t LSTB = (size_t)NN * 128 * 4;
  int* idx0 = (int*)(Atf8);
  float* val0 = (float*)(Atf8 + LSTB);
  int* idx2 = (int*)(Atf8 + 2 * LSTB);
  float* val2 = (float*)(Atf8 + 3 * LSTB);

  // two-plane bf16 C (K split across blocks; readers sum parts=2)
  unsigned short* C = (unsigned short*)alloc((size_t)2 * NN * NN * 2);

  // 1) zero y1/s1 (contiguous 2*NN floats)
  hipMemsetAsync(y1, 0, (size_t)2 * NN * 4, stream);
  // 2) prep: A -> packed fp8 (straight+transposed) + y1/s1 | emb concat
  prep<<<2688, 256, 0, stream>>>(A, vu, vv, Af8, Atf8, y1, s1, uemb, iemb,
                                 allE);
  // 3) A2 = A*A (192-tile, grid-z K-split: 2 independent blocks/CU)
  gemm_f8<<<512, 256, 0, stream>>>(Af8, Atf8, C);
  // 4) post1: topk(A2 partial-sum)+packed fp8 cast | tvec = A.y1
  post1<<<1536, 256, 0, stream>>>(C, 2, A, y1, A2f8, cnts1, tIdx1, tVal1,
                                  tvec);
  // 5) A3 = A2*A (overwrite C planes)
  gemm_f8<<<512, 256, 0, stream>>>(A2f8, Atf8, C);
  // 6) sel02: layer-0 (A) + layer-2 (A3) top-64 lists | post2 fold (bid 1536)
  sel02<<<1537, 256, 0, stream>>>(C, 2, A, cnt0, idx0, val0, cnt2, idx2,
                                  val2, vu, vv, y1, s1, tvec, wacc);
  // 7) gather_light: pure float2 gather, one wave per row
  gather_light<<<768, 256, 0, stream>>>(allE, uemb0, iemb0, wacc, cnt0, idx0,
                                        val0, cnts1, tIdx1, tVal1, cnt2, idx2,
                                        val2, lightOut);
  // 8) gather dots
  out_dot<<<BB / 4, 256, 0, stream>>>(users, items, lightOut, out);
}

// Round 11
// 233.586 us; speedup vs baseline: 1.0282x; 1.0195x over previous
//
#include <hip/hip_runtime.h>
#include <hip/hip_fp8.h>
#include <math.h>

#define NN 3072
#define NU 1024
#define NI 2048
#define DD 128
#define BB 8192
#define GAMMA_F 0.2f

#define SCALE_A 524288.0f                // 2^19
#define F8SCALE2 1.9073486328125e-06f    // 2^-19  (C*2^38 -> A2*2^19 for fp8)
#define DESCALE38 3.637978807091713e-12f // 2^-38  (C -> true A^k values)

// packed fp8 layout: [k/64][row][k%64]; one k-block = NN rows x 64 B
#define KBLK ((size_t)NN * 64)

typedef __attribute__((ext_vector_type(4))) float f32x4;
typedef __attribute__((ext_vector_type(16))) float f32x16;
typedef __attribute__((ext_vector_type(4))) int i32x4;
typedef __attribute__((ext_vector_type(8))) int i32x8;

static __device__ inline unsigned short bf16bits(float x) {
  union { unsigned u; float f; } cv;
  cv.f = x;
  unsigned r = cv.u + 0x7fff + ((cv.u >> 16) & 1);  // RNE
  return (unsigned short)(r >> 16);
}

// pack 4 floats -> 4 fp8 e4m3 (OCP) bytes
static __device__ inline unsigned pk4_f8(float a, float b, float c, float d) {
#if defined(__has_builtin)
#if __has_builtin(__builtin_amdgcn_cvt_pk_fp8_f32)
  int p = __builtin_amdgcn_cvt_pk_fp8_f32(a, b, 0, false);
  p = __builtin_amdgcn_cvt_pk_fp8_f32(c, d, p, true);
  return (unsigned)p;
#else
  return (unsigned)__hip_fp8_e4m3(a).__x | ((unsigned)__hip_fp8_e4m3(b).__x << 8) |
         ((unsigned)__hip_fp8_e4m3(c).__x << 16) |
         ((unsigned)__hip_fp8_e4m3(d).__x << 24);
#endif
#else
  return (unsigned)__hip_fp8_e4m3(a).__x | ((unsigned)__hip_fp8_e4m3(b).__x << 8) |
         ((unsigned)__hip_fp8_e4m3(c).__x << 16) |
         ((unsigned)__hip_fp8_e4m3(d).__x << 24);
#endif
}

static __device__ inline void atomAddF(float* p, float v) {
#if defined(__has_builtin)
#if __has_builtin(__builtin_amdgcn_global_atomic_fadd_f32)
  __builtin_amdgcn_global_atomic_fadd_f32(
      (__attribute__((address_space(1))) float*)p, v);
#else
  unsafeAtomicAdd(p, v);
#endif
#else
  unsafeAtomicAdd(p, v);
#endif
}

static __device__ inline float block_sum(float s, float* red4) {
  int tid = threadIdx.x;
  for (int off = 32; off; off >>= 1) s += __shfl_down(s, off, 64);
  if ((tid & 63) == 0) red4[tid >> 6] = s;
  __syncthreads();
  return red4[0] + red4[1] + red4[2] + red4[3];
}

static __device__ inline float row_dot_f32(const float* __restrict__ a,
                                           const float* __restrict__ b,
                                           float* red4) {
  const float4* ap = (const float4*)a;
  const float4* bp = (const float4*)b;
  float s = 0.f;
  for (int j = threadIdx.x; j < NN / 4; j += 256) {
    float4 x = ap[j], y = bp[j];
    s += x.x * y.x + x.y * y.y + x.z * y.z + x.w * y.w;
  }
  return block_sum(s, red4);
}

// ---------------------------------------------------------------------------
// topk loaders: fill f[48] with this row's values (one wave, 48 vals/lane).
static __device__ inline void load48_bf(const unsigned short* __restrict__ b0,
                                        int parts, int row, int lane,
                                        float* f) {
  const uint4* r0 = (const uint4*)(b0 + (size_t)row * NN);
#pragma unroll
  for (int j = 0; j < 6; ++j) {
    uint4 q = r0[lane + j * 64];
    unsigned uu[4] = {q.x, q.y, q.z, q.w};
#pragma unroll
    for (int e = 0; e < 4; ++e) {
      f[j * 8 + e * 2] = __uint_as_float(uu[e] << 16);
      f[j * 8 + e * 2 + 1] = __uint_as_float(uu[e] & 0xffff0000u);
    }
  }
  for (int p = 1; p < parts; ++p) {
    const uint4* rp = (const uint4*)(b0 + (size_t)p * NN * NN + (size_t)row * NN);
#pragma unroll
    for (int j = 0; j < 6; ++j) {
      uint4 q = rp[lane + j * 64];
      unsigned uu[4] = {q.x, q.y, q.z, q.w};
#pragma unroll
      for (int e = 0; e < 4; ++e) {
        f[j * 8 + e * 2] += __uint_as_float(uu[e] << 16);
        f[j * 8 + e * 2 + 1] += __uint_as_float(uu[e] & 0xffff0000u);
      }
    }
  }
}

static __device__ inline void load48_f32(const float* __restrict__ A, int row,
                                         int lane, float* f) {
  const float4* r0 = (const float4*)(A + (size_t)row * NN);
#pragma unroll
  for (int j = 0; j < 12; ++j) {
    float4 a = r0[lane + j * 64];
    f[j * 4 + 0] = a.x; f[j * 4 + 1] = a.y;
    f[j * 4 + 2] = a.z; f[j * 4 + 3] = a.w;
  }
}

// ---------------------------------------------------------------------------
// select top-64 of the wave's 64x48 values. Radix on bits [30..16], two bits
// per step. v12: ADAPTIVE counting — counts are monotone (c3<=c2<=c1), so
// count the MIDDLE candidate first, then only the side the (wave-uniform)
// branch needs: 48x2 predicated cmps per step instead of 48x3 (-33% hot-loop
// VALU). Butterfly shfl_xor reduces (all lanes get the total). Compact
// (idx*DD, val*scale) into out arrays (128 slots; LDS or global).
static __device__ void select_compact(const float* f, int lane, float descale,
                                      int bf, int* __restrict__ outCnt,
                                      int* __restrict__ outIdx,
                                      float* __restrict__ outVal) {
  unsigned bor = 0, band = 0xffffffffu;
#pragma unroll
  for (int r = 0; r < 48; ++r) {
    unsigned k = __float_as_uint(f[r]);
    bor |= k; band &= k;
  }
  for (int off = 32; off; off >>= 1) {
    bor |= (unsigned)__shfl_xor((int)bor, off, 64);
    band &= (unsigned)__shfl_xor((int)band, off, 64);
  }
  unsigned diff = bor ^ band;
  int hi = diff ? (31 - __clz(diff)) : 16;
  if (hi < 16) hi = 16;
  if (hi > 30) hi = 30;
  unsigned t = band & ~((2u << hi) - 1u);

  int b = hi;
  while (b >= 17) {
    unsigned base = 1u << (b - 1);
    unsigned cand2 = t | (base << 1);  // middle of the 3 candidates
    int c2 = 0;
#pragma unroll
    for (int r = 0; r < 48; ++r) c2 += (__float_as_uint(f[r]) >= cand2) ? 1 : 0;
    for (int off = 32; off; off >>= 1) c2 += __shfl_xor(c2, off, 64);
    if (c2 >= 64) {
      // answer has bit (b) set; test bit (b-1) on top of it
      unsigned cand3 = cand2 | base;
      int c3 = 0;
#pragma unroll
      for (int r = 0; r < 48; ++r)
        c3 += (__float_as_uint(f[r]) >= cand3) ? 1 : 0;
      for (int off = 32; off; off >>= 1) c3 += __shfl_xor(c3, off, 64);
      t = (c3 >= 64) ? cand3 : cand2;
    } else {
      // answer has bit (b) clear; test bit (b-1) alone
      unsigned cand1 = t | base;
      int c1 = 0;
#pragma unroll
      for (int r = 0; r < 48; ++r)
        c1 += (__float_as_uint(f[r]) >= cand1) ? 1 : 0;
      for (int off = 32; off; off >>= 1) c1 += __shfl_xor(c1, off, 64);
      if (c1 >= 64) t = cand1;
    }
    b -= 2;
  }
  if (b == 16) {
    unsigned cand = t | (1u << 16);
    int c = 0;
#pragma unroll
    for (int r = 0; r < 48; ++r) c += (__float_as_uint(f[r]) >= cand) ? 1 : 0;
    for (int off = 32; off; off >>= 1) c += __shfl_xor(c, off, 64);
    if (c >= 64) t = cand;
  }

  int basec = 0;
#pragma unroll
  for (int r = 0; r < 48; ++r) {
    bool keep = __float_as_uint(f[r]) >= t;
    unsigned long long m = __ballot(keep);
    if (keep) {
      int pos = basec + __popcll(m & ((1ull << lane) - 1ull));
      if (pos < 128) {
        int col = bf ? ((r >> 3) * 512 + lane * 8 + (r & 7))
                     : ((r >> 2) * 256 + lane * 4 + (r & 3));
        outIdx[pos] = col << 7;  // pre-scaled by DD for gather addressing
        outVal[pos] = f[r] * descale;
      }
    }
    basec += __popcll(m);
  }
  if (lane == 0) *outCnt = basec < 128 ? basec : 128;
}

// ---------------------------------------------------------------------------
// prep: A -> fp8 PACKED (straight + transposed, x2^19) + fused y1/s1 matvec
// partials. blocks [0,2304): 48x48 tiles of 64x64; blocks [2304,2688):
// concat uemb/iemb -> allE.
// v12: phase-1 (straight pack) packs DIRECTLY FROM REGISTERS — each thread
// owns 16 row-contiguous floats (r = t>>2, ch = t&3), loads 4x float4,
// packs, and stores to LDS only for the transpose/matvec phases. Removes a
// full LDS read phase vs v11 (which loaded -> LDS -> re-read for pack).
__global__ __launch_bounds__(256) void prep(
    const float* __restrict__ A, const float* __restrict__ vu,
    const float* __restrict__ vv, unsigned char* __restrict__ Af8,
    unsigned char* __restrict__ Atf8, float* __restrict__ y1,
    float* __restrict__ s1, const float* __restrict__ uemb,
    const float* __restrict__ iemb, float* __restrict__ allE) {
  __shared__ float sh[64 * 65 + 512];
  const int bid = blockIdx.x;
  const int t = threadIdx.x;
  if (bid >= 2304) {
    int idx = (bid - 2304) * 256 + t;
    int e = idx * 4;
    float4 v = (e < NU * DD) ? *(const float4*)(uemb + e)
                             : *(const float4*)(iemb + (e - NU * DD));
    *(float4*)(allE + e) = v;
    return;
  }
  const int bx = (bid % 48) * 64, by = (bid / 48) * 64;
  {
    const int r = t >> 2;   // 0..63
    const int ch = t & 3;   // 16-float chunk
    float v16[16];
    const float* arow = A + (size_t)(by + r) * NN + bx + ch * 16;
#pragma unroll
    for (int q4 = 0; q4 < 4; ++q4) {
      float4 val = *(const float4*)(arow + q4 * 4);
      v16[q4 * 4 + 0] = val.x; v16[q4 * 4 + 1] = val.y;
      v16[q4 * 4 + 2] = val.z; v16[q4 * 4 + 3] = val.w;
      float* sp = &sh[r * 65 + ch * 16 + q4 * 4];
      sp[0] = val.x; sp[1] = val.y; sp[2] = val.z; sp[3] = val.w;
    }
    uint4 w;
    w.x = pk4_f8(v16[0] * SCALE_A, v16[1] * SCALE_A, v16[2] * SCALE_A,
                 v16[3] * SCALE_A);
    w.y = pk4_f8(v16[4] * SCALE_A, v16[5] * SCALE_A, v16[6] * SCALE_A,
                 v16[7] * SCALE_A);
    w.z = pk4_f8(v16[8] * SCALE_A, v16[9] * SCALE_A, v16[10] * SCALE_A,
                 v16[11] * SCALE_A);
    w.w = pk4_f8(v16[12] * SCALE_A, v16[13] * SCALE_A, v16[14] * SCALE_A,
                 v16[15] * SCALE_A);
    *(uint4*)(Af8 + (size_t)(bx >> 6) * KBLK + (size_t)(by + r) * 64 +
              ch * 16) = w;
  }
  __syncthreads();
  {
    int c = t >> 2, ch = t & 3;
    float v[16];
#pragma unroll
    for (int e = 0; e < 16; ++e) v[e] = sh[(ch * 16 + e) * 65 + c];
    uint4 w;
    w.x = pk4_f8(v[0] * SCALE_A, v[1] * SCALE_A, v[2] * SCALE_A,
                 v[3] * SCALE_A);
    w.y = pk4_f8(v[4] * SCALE_A, v[5] * SCALE_A, v[6] * SCALE_A,
                 v[7] * SCALE_A);
    w.z = pk4_f8(v[8] * SCALE_A, v[9] * SCALE_A, v[10] * SCALE_A,
                 v[11] * SCALE_A);
    w.w = pk4_f8(v[12] * SCALE_A, v[13] * SCALE_A, v[14] * SCALE_A,
                 v[15] * SCALE_A);
    *(uint4*)(Atf8 + (size_t)(by >> 6) * KBLK + (size_t)(bx + c) * 64 +
              ch * 16) = w;
  }
  const int q = t >> 6;
  const int l = t & 63;
  float sy = 0.f, ss_ = 0.f;
  for (int i = 0; i < 16; ++i) {
    int c = q * 16 + i;
    sy += sh[l * 65 + c] * vv[bx + c];
    ss_ += vu[by + c] * sh[c * 65 + l];
  }
  float* red = sh + 64 * 65;
  red[q * 64 + l] = sy;
  red[256 + q * 64 + l] = ss_;
  __syncthreads();
  if (t < 64) {
    float v4 = red[t] + red[64 + t] + red[128 + t] + red[192 + t];
    atomAddF(&y1[by + t], v4);
  } else if (t < 128) {
    int cc = t - 64;
    float v4 = red[256 + cc] + red[256 + 64 + cc] + red[256 + 128 + cc] +
               red[256 + 192 + cc];
    atomAddF(&s1[bx + cc], v4);
  }
}

// ---------------------------------------------------------------------------
// gemm_f8 v11 (kept): 192x192 tile, 4 waves, K split across blocks (grid
// 512, z = K-half), 3-buffer counted-vmcnt LDS pipeline, 2 blocks/CU.
static __device__ inline i32x8 ldfragL(const char* p) {
  i32x4 lo = *(const i32x4*)p;
  i32x4 hi = *(const i32x4*)(p + 1024);
  return (i32x8){lo.x, lo.y, lo.z, lo.w, hi.x, hi.y, hi.z, hi.w};
}

__global__ __launch_bounds__(256, 2) void gemm_f8(
    const unsigned char* __restrict__ Ag,
    const unsigned char* __restrict__ Btg,
    unsigned short* __restrict__ Cg) {
  __shared__ char smem[3][24576];  // 72 KiB -> 2 blocks/CU
  const int wg = blockIdx.x;
  const int xcd = wg & 7;
  const int idx = wg >> 3;             // 0..63
  const int bxi = xcd * 2 + (idx & 1); // column panel 0..15
  const int byi = (idx >> 1) & 15;     // row panel    0..15
  const int z = idx >> 5;              // K-half 0/1
  const int rowBase = byi * 192, colBase = bxi * 192;

  const int t = threadIdx.x;
  const int w = t >> 6, l = t & 63;
  const int wr = w >> 1, wc = w & 1;
  const int r32 = l & 31, hh = l >> 5;

  f32x16 acc[3][3];
#pragma unroll
  for (int i = 0; i < 3; ++i)
#pragma unroll
    for (int j = 0; j < 3; ++j)
#pragma unroll
      for (int e = 0; e < 16; ++e) acc[i][j][e] = 0.f;

  const unsigned char* aT = Ag + (size_t)rowBase * 64;
  const unsigned char* bT = Btg + (size_t)colBase * 64;
  const int laneOff = r32 * 64 + hh * 32;
  const int kt0 = z * 24;  // this block's K-tile range: [kt0, kt0+24)

#define STAGE(kt, b)                                                        \
  {                                                                         \
    const size_t kOff = (size_t)(kt) * KBLK;                                \
    _Pragma("unroll") for (int r_ = 0; r_ < 6; ++r_) {                      \
      int q_ = r_ * 4 + w;                                                  \
      int qq_ = q_ < 12 ? q_ : q_ - 12;                                     \
      int s_ = qq_ >> 1, h_ = qq_ & 1;                                      \
      const unsigned char* g_ = ((q_ < 12) ? aT : bT) + kOff +              \
                                (size_t)(s_ * 32) * 64 + laneOff + h_ * 16; \
      __builtin_amdgcn_global_load_lds(                                     \
          (const __attribute__((address_space(1))) unsigned*)g_,            \
          (__attribute__((address_space(3))) unsigned*)(smem[b] +           \
                                                        q_ * 1024),         \
          16, 0, 0);                                                        \
    }                                                                       \
  }

  const int ni = 24;
  STAGE(kt0, 0);
  STAGE(kt0 + 1, 1);
  for (int i = 0; i < ni; ++i) {
    if (i < ni - 1) {
      asm volatile("s_waitcnt vmcnt(6)" ::: "memory");
    } else {
      asm volatile("s_waitcnt vmcnt(0)" ::: "memory");
    }
    __builtin_amdgcn_s_barrier();
    __builtin_amdgcn_sched_barrier(0);
    const char* sb = smem[i % 3];
    i32x8 af[3], bfr[3];
#pragma unroll
    for (int ii = 0; ii < 3; ++ii)
      af[ii] = ldfragL(sb + (wr * 3 + ii) * 2048 + l * 16);
#pragma unroll
    for (int j = 0; j < 3; ++j)
      bfr[j] = ldfragL(sb + 12288 + (wc * 3 + j) * 2048 + l * 16);
    if (i + 2 < ni) STAGE(kt0 + i + 2, (i + 2) % 3);
    __builtin_amdgcn_s_setprio(1);
#pragma unroll
    for (int ii = 0; ii < 3; ++ii)
#pragma unroll
      for (int j = 0; j < 3; ++j)
        acc[ii][j] = __builtin_amdgcn_mfma_scale_f32_32x32x64_f8f6f4(
            af[ii], bfr[j], acc[ii][j], 0, 0, 0, 127, 0, 127);
    __builtin_amdgcn_s_setprio(0);
    __builtin_amdgcn_sched_barrier(0);
  }
#undef STAGE

  // C/D 32x32 layout: col = lane&31, row = (reg&3) + 8*(reg>>2) + 4*(lane>>5)
  unsigned short* Cout = Cg + (size_t)z * NN * NN;
#pragma unroll
  for (int i = 0; i < 3; ++i) {
    int rb = rowBase + wr * 96 + i * 32 + 4 * hh;
#pragma unroll
    for (int j = 0; j < 3; ++j) {
      int cc = colBase + wc * 96 + j * 32 + r32;
#pragma unroll
      for (int reg = 0; reg < 16; ++reg) {
        int rr = rb + (reg & 3) + 8 * (reg >> 2);
        Cout[(size_t)rr * NN + cc] = bf16bits(acc[i][j][reg]);
      }
    }
  }
}

// ---------------------------------------------------------------------------
// post1: [0,768)     topk(A2 bf16 partial-sum) + packed fp8 cast -> A2f8
//        [768,1536)  tvec = A.y1 (one wave per row)
__global__ __launch_bounds__(256) void post1(
    const unsigned short* __restrict__ C, int parts,
    const float* __restrict__ A, const float* __restrict__ y1,
    unsigned char* __restrict__ A2f8, int* __restrict__ cnts1,
    int* __restrict__ tIdx1, float* __restrict__ tVal1,
    float* __restrict__ tvec) {
  const int bid = blockIdx.x;
  const int t = threadIdx.x;
  if (bid < 768) {
    int row = bid * 4 + (t >> 6);
    int lane = t & 63;
    float f[48];
    load48_bf(C, parts, row, lane, f);
    // fused packed fp8 cast: f[j*8+e] = col k0+e, k0=(j*64+lane)*8
#pragma unroll
    for (int j = 0; j < 6; ++j) {
      uint2 w;
      w.x = pk4_f8(f[j * 8 + 0] * F8SCALE2, f[j * 8 + 1] * F8SCALE2,
                   f[j * 8 + 2] * F8SCALE2, f[j * 8 + 3] * F8SCALE2);
      w.y = pk4_f8(f[j * 8 + 4] * F8SCALE2, f[j * 8 + 5] * F8SCALE2,
                   f[j * 8 + 6] * F8SCALE2, f[j * 8 + 7] * F8SCALE2);
      size_t addr = (size_t)(j * 8 + (lane >> 3)) * KBLK +
                    (size_t)row * 64 + (lane & 7) * 8;
      *(uint2*)(A2f8 + addr) = w;
    }
    select_compact(f, lane, DESCALE38, 1, &cnts1[row],
                   tIdx1 + (size_t)row * 128, tVal1 + (size_t)row * 128);
  } else {
    int row = (bid - 768) * 4 + (t >> 6);
    int lane = t & 63;
    const float4* rp = (const float4*)(A + (size_t)row * NN);
    const float4* yp = (const float4*)y1;
    float s = 0.f;
#pragma unroll
    for (int j = 0; j < 12; ++j) {
      float4 a = rp[lane + j * 64];
      float4 y = yp[lane + j * 64];
      s += a.x * y.x + a.y * y.y + a.z * y.z + a.w * y.w;
    }
    for (int off = 32; off; off >>= 1) s += __shfl_down(s, off, 64);
    if (lane == 0) tvec[row] = s;
  }
}

// ---------------------------------------------------------------------------
// sel02: phase-homogeneous select kernel (one select per wave, dense waves).
//   bid < 1536, even: layer-2 lists from C (A3 bf16 partials) -> global
//   bid < 1536, odd:  layer-0 lists from A (fp32)             -> global
//   bid == 1536:      post2 fold (w0..w3 -> wacc)
__global__ __launch_bounds__(256) void sel02(
    const unsigned short* __restrict__ C, int parts,
    const float* __restrict__ A, int* __restrict__ cnt0,
    int* __restrict__ idx0, float* __restrict__ val0,
    int* __restrict__ cnt2, int* __restrict__ idx2,
    float* __restrict__ val2, const float* __restrict__ vu,
    const float* __restrict__ vv, const float* __restrict__ y1,
    const float* __restrict__ s1, const float* __restrict__ tvec,
    float* __restrict__ wacc) {
  __shared__ float red4[4];
  const int bid = blockIdx.x;
  const int t = threadIdx.x;
  if (bid == 1536) {
    float w0 = row_dot_f32(vu, vv, red4);  __syncthreads();
    float w1 = row_dot_f32(vu, y1, red4);  __syncthreads();
    float w2 = row_dot_f32(s1, y1, red4);  __syncthreads();
    float w3 = row_dot_f32(s1, tvec, red4);
    if (t == 0) { wacc[0] = w0; wacc[1] = w1; wacc[2] = w2; wacc[3] = w3; }
    return;
  }
  const int w = t >> 6, lane = t & 63;
  const int row = (bid >> 1) * 4 + w;
  float f[48];
  if ((bid & 1) == 0) {
    load48_bf(C, parts, row, lane, f);
    select_compact(f, lane, DESCALE38, 1, &cnt2[row],
                   idx2 + (size_t)row * 128, val2 + (size_t)row * 128);
  } else {
    load48_f32(A, row, lane, f);
    select_compact(f, lane, 1.0f, 0, &cnt0[row],
                   idx0 + (size_t)row * 128, val0 + (size_t)row * 128);
  }
}

// ---------------------------------------------------------------------------
// gather_light: pure gather, one wave per row (768 blocks x 256 thr).
__global__ __launch_bounds__(256) void gather_light(
    const float* __restrict__ allE, const float* __restrict__ uemb0,
    const float* __restrict__ iemb0, const float* __restrict__ wacc,
    const int* __restrict__ cnt0, const int* __restrict__ idx0,
    const float* __restrict__ val0, const int* __restrict__ cnts1,
    const int* __restrict__ tIdx1, const float* __restrict__ tVal1,
    const int* __restrict__ cnt2, const int* __restrict__ idx2,
    const float* __restrict__ val2, float* __restrict__ lightOut) {
  __shared__ int li[4][384];
  __shared__ float lv[4][384];
  const int t = threadIdx.x;
  const int w = t >> 6, lane = t & 63;
  const int row = blockIdx.x * 4 + w;

  float w0 = wacc[0], w1 = wacc[1], w2 = wacc[2], w3 = wacc[3];
  float ss = w0 + w1 + w2 + w3;
  w0 /= ss; w1 /= ss; w2 /= ss; w3 /= ss;
  float m = fmaxf(fmaxf(w0, w1), fmaxf(w2, w3));
  float ex0 = expf(w0 - m), ex1 = expf(w1 - m), ex2 = expf(w2 - m),
        ex3 = expf(w3 - m);
  float se = ex0 + ex1 + ex2 + ex3;
  float aw0 = ex0 / se, aw1 = ex1 / se, aw2 = ex2 / se, aw3 = ex3 / se;
  float aw4 = GAMMA_F * (aw1 + aw2 + aw3);

  const int c0 = cnt0[row], c1 = cnts1[row], c2 = cnt2[row];
  const int p0 = (c0 + 7) & ~7, p1 = (c1 + 7) & ~7, p2 = (c2 + 7) & ~7;
  int* Li = li[w];
  float* Lv = lv[w];
  const size_t rb = (size_t)row * 128;
  for (int k = lane; k < p0; k += 64) {
    bool in = k < c0;
    Li[k] = in ? idx0[rb + k] : 0;
    Lv[k] = in ? aw1 * val0[rb + k] : 0.f;
  }
  for (int k = lane; k < p1; k += 64) {
    bool in = k < c1;
    Li[p0 + k] = in ? tIdx1[rb + k] : 0;
    Lv[p0 + k] = in ? aw2 * tVal1[rb + k] : 0.f;
  }
  for (int k = lane; k < p2; k += 64) {
    bool in = k < c2;
    Li[p0 + p1 + k] = in ? idx2[rb + k] : 0;
    Lv[p0 + p1 + k] = in ? aw3 * val2[rb + k] : 0.f;
  }
  // same-wave produce->consume through LDS: compiler orders via lgkmcnt.

  const int ct = p0 + p1 + p2;
  const float2* E2 = (const float2*)allE;
  float ax = 0.f, ay = 0.f, bx_ = 0.f, by_ = 0.f;
  for (int k = 0; k < ct; k += 8) {
    int i0 = Li[k + 0], i1 = Li[k + 1], i2 = Li[k + 2], i3 = Li[k + 3];
    int i4 = Li[k + 4], i5 = Li[k + 5], i6 = Li[k + 6], i7 = Li[k + 7];
    float v0 = Lv[k + 0], v1 = Lv[k + 1], v2 = Lv[k + 2], v3 = Lv[k + 3];
    float v4 = Lv[k + 4], v5 = Lv[k + 5], v6 = Lv[k + 6], v7 = Lv[k + 7];
    float2 g0 = E2[(i0 >> 1) + lane];
    float2 g1 = E2[(i1 >> 1) + lane];
    float2 g2 = E2[(i2 >> 1) + lane];
    float2 g3 = E2[(i3 >> 1) + lane];
    float2 g4 = E2[(i4 >> 1) + lane];
    float2 g5 = E2[(i5 >> 1) + lane];
    float2 g6 = E2[(i6 >> 1) + lane];
    float2 g7 = E2[(i7 >> 1) + lane];
    ax += v0 * g0.x; ay += v0 * g0.y;
    bx_ += v1 * g1.x; by_ += v1 * g1.y;
    ax += v2 * g2.x; ay += v2 * g2.y;
    bx_ += v3 * g3.x; by_ += v3 * g3.y;
    ax += v4 * g4.x; ay += v4 * g4.y;
    bx_ += v5 * g5.x; by_ += v5 * g5.y;
    ax += v6 * g6.x; ay += v6 * g6.y;
    bx_ += v7 * g7.x; by_ += v7 * g7.y;
  }
  float2 sE = E2[((size_t)row << 6) + lane];
  float2 e0 = (row < NU)
                  ? ((const float2*)uemb0)[(size_t)row * 64 + lane]
                  : ((const float2*)iemb0)[(size_t)(row - NU) * 64 + lane];
  float ox = (ax + bx_) + aw0 * sE.x + aw4 * e0.x;
  float oy = (ay + by_) + aw0 * sE.y + aw4 * e0.y;
  float2 o; o.x = ox; o.y = oy;
  ((float2*)lightOut)[(size_t)row * 64 + lane] = o;
}

__global__ __launch_bounds__(256) void out_dot(const int* __restrict__ users,
                                               const int* __restrict__ items,
                                               const float* __restrict__ lightOut,
                                               float* __restrict__ out) {
  int b = blockIdx.x * 4 + (threadIdx.x >> 6);
  int lane = threadIdx.x & 63;
  const float* up = lightOut + (size_t)users[b] * DD;
  const float* ip = lightOut + (size_t)(NU + items[b]) * DD;
  float s = up[lane] * ip[lane] + up[lane + 64] * ip[lane + 64];
  for (int off = 32; off; off >>= 1) s += __shfl_down(s, off, 64);
  if (lane == 0) out[b] = s;
}

// ---------------------------------------------------------------------------
extern "C" void kernel_launch(void* const* d_in, const int* in_sizes, int n_in,
                              void* d_out, int out_size, void* d_ws,
                              size_t ws_size, hipStream_t stream) {
  const int* users = (const int*)d_in[0];
  const int* items = (const int*)d_in[1];
  const float* A = (const float*)d_in[2];
  const float* uemb = (const float*)d_in[3];
  const float* iemb = (const float*)d_in[4];
  const float* uemb0 = (const float*)d_in[5];
  const float* iemb0 = (const float*)d_in[6];
  const float* vu = (const float*)d_in[7];
  const float* vv = (const float*)d_in[8];
  float* out = (float*)d_out;

  char* ws = (char*)d_ws;
  size_t off = 0;
  auto alloc = [&](size_t bytes) -> void* {
    void* p = ws + off;
    off += (bytes + 255) & ~(size_t)255;
    return p;
  };
  unsigned char* Af8 = (unsigned char*)alloc((size_t)NN * NN);
  unsigned char* Atf8 = (unsigned char*)alloc((size_t)NN * NN);
  unsigned char* A2f8 = (unsigned char*)alloc((size_t)NN * NN);
  float* y1 = (float*)alloc((size_t)NN * 4);   // contiguous with s1
  float* s1 = (float*)alloc((size_t)NN * 4);
  float* tvec = (float*)alloc((size_t)NN * 4);
  float* wacc = (float*)alloc(256);
  int* cnts1 = (int*)alloc((size_t)NN * 4);
  int* tIdx1 = (int*)alloc((size_t)NN * 128 * 4);
  float* tVal1 = (float*)alloc((size_t)NN * 128 * 4);
  float* lightOut = (float*)alloc((size_t)NN * DD * 4);
  int* cnt0 = (int*)alloc((size_t)NN * 4);
  int* cnt2 = (int*)alloc((size_t)NN * 4);
  float* allE = (float*)alloc((size_t)NN * DD * 4);  // dedicated (no alias)

  // layer-0/2 lists (4 x 1.5 MB) alias Atf8 (9.4 MB): Atf8 is dead after
  // gemm#2 (step 5); sel02 (step 6) writes, gather (step 8) reads.
  const size_t LSTB = (size_t)NN * 128 * 4;
  int* idx0 = (int*)(Atf8);
  float* val0 = (float*)(Atf8 + LSTB);
  int* idx2 = (int*)(Atf8 + 2 * LSTB);
  float* val2 = (float*)(Atf8 + 3 * LSTB);

  // two-plane bf16 C (K split across blocks; readers sum parts=2)
  unsigned short* C = (unsigned short*)alloc((size_t)2 * NN * NN * 2);

  // 1) zero y1/s1 (contiguous 2*NN floats)
  hipMemsetAsync(y1, 0, (size_t)2 * NN * 4, stream);
  // 2) prep: A -> packed fp8 (reg-direct straight pack + LDS transpose) |
  //    y1/s1 partials | emb concat
  prep<<<2688, 256, 0, stream>>>(A, vu, vv, Af8, Atf8, y1, s1, uemb, iemb,
                                 allE);
  // 3) A2 = A*A (192-tile, grid-z K-split: 2 independent blocks/CU)
  gemm_f8<<<512, 256, 0, stream>>>(Af8, Atf8, C);
  // 4) post1: topk(A2 partial-sum, adaptive radix)+fp8 cast | tvec = A.y1
  post1<<<1536, 256, 0, stream>>>(C, 2, A, y1, A2f8, cnts1, tIdx1, tVal1,
                                  tvec);
  // 5) A3 = A2*A (overwrite C planes)
  gemm_f8<<<512, 256, 0, stream>>>(A2f8, Atf8, C);
  // 6) sel02: layer-0 (A) + layer-2 (A3) top-64 lists | post2 fold (bid 1536)
  sel02<<<1537, 256, 0, stream>>>(C, 2, A, cnt0, idx0, val0, cnt2, idx2,
                                  val2, vu, vv, y1, s1, tvec, wacc);
  // 7) gather_light: pure float2 gather, one wave per row
  gather_light<<<768, 256, 0, stream>>>(allE, uemb0, iemb0, wacc, cnt0, idx0,
                                        val0, cnts1, tIdx1, tVal1, cnt2, idx2,
                                        val2, lightOut);
  // 8) gather dots
  out_dot<<<BB / 4, 256, 0, stream>>>(users, items, lightOut, out);
}

// Round 12
// 231.939 us; speedup vs baseline: 1.0355x; 1.0071x over previous
//
#include <hip/hip_runtime.h>
#include <hip/hip_fp8.h>
#include <math.h>

#define NN 3072
#define NU 1024
#define NI 2048
#define DD 128
#define BB 8192
#define GAMMA_F 0.2f

#define SCALE_A 524288.0f                // 2^19
#define F8SCALE2 1.9073486328125e-06f    // 2^-19  (C*2^38 -> A2*2^19 for fp8)
#define DESCALE38 3.637978807091713e-12f // 2^-38  (C -> true A^k values)

// packed fp8 layout: [k/64][row][k%64]; one k-block = NN rows x 64 B
#define KBLK ((size_t)NN * 64)

typedef __attribute__((ext_vector_type(4))) float f32x4;
typedef __attribute__((ext_vector_type(16))) float f32x16;
typedef __attribute__((ext_vector_type(4))) int i32x4;
typedef __attribute__((ext_vector_type(8))) int i32x8;

static __device__ inline unsigned short bf16bits(float x) {
  union { unsigned u; float f; } cv;
  cv.f = x;
  unsigned r = cv.u + 0x7fff + ((cv.u >> 16) & 1);  // RNE
  return (unsigned short)(r >> 16);
}

// pack 4 floats -> 4 fp8 e4m3 (OCP) bytes
static __device__ inline unsigned pk4_f8(float a, float b, float c, float d) {
#if defined(__has_builtin)
#if __has_builtin(__builtin_amdgcn_cvt_pk_fp8_f32)
  int p = __builtin_amdgcn_cvt_pk_fp8_f32(a, b, 0, false);
  p = __builtin_amdgcn_cvt_pk_fp8_f32(c, d, p, true);
  return (unsigned)p;
#else
  return (unsigned)__hip_fp8_e4m3(a).__x | ((unsigned)__hip_fp8_e4m3(b).__x << 8) |
         ((unsigned)__hip_fp8_e4m3(c).__x << 16) |
         ((unsigned)__hip_fp8_e4m3(d).__x << 24);
#endif
#else
  return (unsigned)__hip_fp8_e4m3(a).__x | ((unsigned)__hip_fp8_e4m3(b).__x << 8) |
         ((unsigned)__hip_fp8_e4m3(c).__x << 16) |
         ((unsigned)__hip_fp8_e4m3(d).__x << 24);
#endif
}

static __device__ inline void atomAddF(float* p, float v) {
#if defined(__has_builtin)
#if __has_builtin(__builtin_amdgcn_global_atomic_fadd_f32)
  __builtin_amdgcn_global_atomic_fadd_f32(
      (__attribute__((address_space(1))) float*)p, v);
#else
  unsafeAtomicAdd(p, v);
#endif
#else
  unsafeAtomicAdd(p, v);
#endif
}

static __device__ inline float block_sum(float s, float* red4) {
  int tid = threadIdx.x;
  for (int off = 32; off; off >>= 1) s += __shfl_down(s, off, 64);
  if ((tid & 63) == 0) red4[tid >> 6] = s;
  __syncthreads();
  return red4[0] + red4[1] + red4[2] + red4[3];
}

static __device__ inline float row_dot_f32(const float* __restrict__ a,
                                           const float* __restrict__ b,
                                           float* red4) {
  const float4* ap = (const float4*)a;
  const float4* bp = (const float4*)b;
  float s = 0.f;
  for (int j = threadIdx.x; j < NN / 4; j += 256) {
    float4 x = ap[j], y = bp[j];
    s += x.x * y.x + x.y * y.y + x.z * y.z + x.w * y.w;
  }
  return block_sum(s, red4);
}

// ---------------------------------------------------------------------------
// topk loaders: fill f[48] with this row's values (one wave, 48 vals/lane).
// parts=1 only (single C plane).
static __device__ inline void load48_bf(const unsigned short* __restrict__ b0,
                                        int row, int lane, float* f) {
  const uint4* r0 = (const uint4*)(b0 + (size_t)row * NN);
#pragma unroll
  for (int j = 0; j < 6; ++j) {
    uint4 q = r0[lane + j * 64];
    unsigned uu[4] = {q.x, q.y, q.z, q.w};
#pragma unroll
    for (int e = 0; e < 4; ++e) {
      f[j * 8 + e * 2] = __uint_as_float(uu[e] << 16);
      f[j * 8 + e * 2 + 1] = __uint_as_float(uu[e] & 0xffff0000u);
    }
  }
}

static __device__ inline void load48_f32(const float* __restrict__ A, int row,
                                         int lane, float* f) {
  const float4* r0 = (const float4*)(A + (size_t)row * NN);
#pragma unroll
  for (int j = 0; j < 12; ++j) {
    float4 a = r0[lane + j * 64];
    f[j * 4 + 0] = a.x; f[j * 4 + 1] = a.y;
    f[j * 4 + 2] = a.z; f[j * 4 + 3] = a.w;
  }
}

// ---------------------------------------------------------------------------
// select top-64 of the wave's 64x48 values. Radix on bits [30..16], two bits
// per step with ADAPTIVE counting (v12: middle candidate first, then only
// the needed side — 48x2 cmps/step). v13: PREFIX-SUM COMPACT — per-lane
// keep-count + one 6-step shfl_up exclusive scan + lane-local writes,
// replacing 48x{ballot+2 popcll} (only ~64/3072 candidates survive; output
// order is lane-major, consumer is an unordered weighted sum).
static __device__ void select_compact(const float* f, int lane, float descale,
                                      int bf, int* __restrict__ outCnt,
                                      int* __restrict__ outIdx,
                                      float* __restrict__ outVal) {
  unsigned bor = 0, band = 0xffffffffu;
#pragma unroll
  for (int r = 0; r < 48; ++r) {
    unsigned k = __float_as_uint(f[r]);
    bor |= k; band &= k;
  }
  for (int off = 32; off; off >>= 1) {
    bor |= (unsigned)__shfl_xor((int)bor, off, 64);
    band &= (unsigned)__shfl_xor((int)band, off, 64);
  }
  unsigned diff = bor ^ band;
  int hi = diff ? (31 - __clz(diff)) : 16;
  if (hi < 16) hi = 16;
  if (hi > 30) hi = 30;
  unsigned t = band & ~((2u << hi) - 1u);

  int b = hi;
  while (b >= 17) {
    unsigned base = 1u << (b - 1);
    unsigned cand2 = t | (base << 1);  // middle of the 3 candidates
    int c2 = 0;
#pragma unroll
    for (int r = 0; r < 48; ++r) c2 += (__float_as_uint(f[r]) >= cand2) ? 1 : 0;
    for (int off = 32; off; off >>= 1) c2 += __shfl_xor(c2, off, 64);
    if (c2 >= 64) {
      unsigned cand3 = cand2 | base;
      int c3 = 0;
#pragma unroll
      for (int r = 0; r < 48; ++r)
        c3 += (__float_as_uint(f[r]) >= cand3) ? 1 : 0;
      for (int off = 32; off; off >>= 1) c3 += __shfl_xor(c3, off, 64);
      t = (c3 >= 64) ? cand3 : cand2;
    } else {
      unsigned cand1 = t | base;
      int c1 = 0;
#pragma unroll
      for (int r = 0; r < 48; ++r)
        c1 += (__float_as_uint(f[r]) >= cand1) ? 1 : 0;
      for (int off = 32; off; off >>= 1) c1 += __shfl_xor(c1, off, 64);
      if (c1 >= 64) t = cand1;
    }
    b -= 2;
  }
  if (b == 16) {
    unsigned cand = t | (1u << 16);
    int c = 0;
#pragma unroll
    for (int r = 0; r < 48; ++r) c += (__float_as_uint(f[r]) >= cand) ? 1 : 0;
    for (int off = 32; off; off >>= 1) c += __shfl_xor(c, off, 64);
    if (c >= 64) t = cand;
  }

  // prefix-sum compact
  int myc = 0;
#pragma unroll
  for (int r = 0; r < 48; ++r)
    myc += (__float_as_uint(f[r]) >= t) ? 1 : 0;
  int scan = myc;  // inclusive scan across 64 lanes
  for (int off = 1; off < 64; off <<= 1) {
    int n = __shfl_up(scan, off, 64);
    if (lane >= off) scan += n;
  }
  int pos = scan - myc;  // exclusive prefix
#pragma unroll
  for (int r = 0; r < 48; ++r) {
    if (__float_as_uint(f[r]) >= t) {
      if (pos < 128) {
        int col = bf ? ((r >> 3) * 512 + lane * 8 + (r & 7))
                     : ((r >> 2) * 256 + lane * 4 + (r & 3));
        outIdx[pos] = col << 7;  // pre-scaled by DD for gather addressing
        outVal[pos] = f[r] * descale;
      }
      ++pos;
    }
  }
  int total = __shfl(scan, 63, 64);
  if (lane == 0) *outCnt = total < 128 ? total : 128;
}

// ---------------------------------------------------------------------------
// prep: A -> fp8 PACKED (straight + transposed, x2^19) + fused y1/s1 matvec
// partials. blocks [0,2304): 48x48 tiles of 64x64; blocks [2304,2688):
// concat uemb/iemb -> allE. Straight pack is reg-direct (v12).
__global__ __launch_bounds__(256) void prep(
    const float* __restrict__ A, const float* __restrict__ vu,
    const float* __restrict__ vv, unsigned char* __restrict__ Af8,
    unsigned char* __restrict__ Atf8, float* __restrict__ y1,
    float* __restrict__ s1, const float* __restrict__ uemb,
    const float* __restrict__ iemb, float* __restrict__ allE) {
  __shared__ float sh[64 * 65 + 512];
  const int bid = blockIdx.x;
  const int t = threadIdx.x;
  if (bid >= 2304) {
    int idx = (bid - 2304) * 256 + t;
    int e = idx * 4;
    float4 v = (e < NU * DD) ? *(const float4*)(uemb + e)
                             : *(const float4*)(iemb + (e - NU * DD));
    *(float4*)(allE + e) = v;
    return;
  }
  const int bx = (bid % 48) * 64, by = (bid / 48) * 64;
  {
    const int r = t >> 2;   // 0..63
    const int ch = t & 3;   // 16-float chunk
    float v16[16];
    const float* arow = A + (size_t)(by + r) * NN + bx + ch * 16;
#pragma unroll
    for (int q4 = 0; q4 < 4; ++q4) {
      float4 val = *(const float4*)(arow + q4 * 4);
      v16[q4 * 4 + 0] = val.x; v16[q4 * 4 + 1] = val.y;
      v16[q4 * 4 + 2] = val.z; v16[q4 * 4 + 3] = val.w;
      float* sp = &sh[r * 65 + ch * 16 + q4 * 4];
      sp[0] = val.x; sp[1] = val.y; sp[2] = val.z; sp[3] = val.w;
    }
    uint4 w;
    w.x = pk4_f8(v16[0] * SCALE_A, v16[1] * SCALE_A, v16[2] * SCALE_A,
                 v16[3] * SCALE_A);
    w.y = pk4_f8(v16[4] * SCALE_A, v16[5] * SCALE_A, v16[6] * SCALE_A,
                 v16[7] * SCALE_A);
    w.z = pk4_f8(v16[8] * SCALE_A, v16[9] * SCALE_A, v16[10] * SCALE_A,
                 v16[11] * SCALE_A);
    w.w = pk4_f8(v16[12] * SCALE_A, v16[13] * SCALE_A, v16[14] * SCALE_A,
                 v16[15] * SCALE_A);
    *(uint4*)(Af8 + (size_t)(bx >> 6) * KBLK + (size_t)(by + r) * 64 +
              ch * 16) = w;
  }
  __syncthreads();
  {
    int c = t >> 2, ch = t & 3;
    float v[16];
#pragma unroll
    for (int e = 0; e < 16; ++e) v[e] = sh[(ch * 16 + e) * 65 + c];
    uint4 w;
    w.x = pk4_f8(v[0] * SCALE_A, v[1] * SCALE_A, v[2] * SCALE_A,
                 v[3] * SCALE_A);
    w.y = pk4_f8(v[4] * SCALE_A, v[5] * SCALE_A, v[6] * SCALE_A,
                 v[7] * SCALE_A);
    w.z = pk4_f8(v[8] * SCALE_A, v[9] * SCALE_A, v[10] * SCALE_A,
                 v[11] * SCALE_A);
    w.w = pk4_f8(v[12] * SCALE_A, v[13] * SCALE_A, v[14] * SCALE_A,
                 v[15] * SCALE_A);
    *(uint4*)(Atf8 + (size_t)(by >> 6) * KBLK + (size_t)(bx + c) * 64 +
              ch * 16) = w;
  }
  const int q = t >> 6;
  const int l = t & 63;
  float sy = 0.f, ss_ = 0.f;
  for (int i = 0; i < 16; ++i) {
    int c = q * 16 + i;
    sy += sh[l * 65 + c] * vv[bx + c];
    ss_ += vu[by + c] * sh[c * 65 + l];
  }
  float* red = sh + 64 * 65;
  red[q * 64 + l] = sy;
  red[256 + q * 64 + l] = ss_;
  __syncthreads();
  if (t < 64) {
    float v4 = red[t] + red[64 + t] + red[128 + t] + red[192 + t];
    atomAddF(&y1[by + t], v4);
  } else if (t < 128) {
    int cc = t - 64;
    float v4 = red[256 + cc] + red[256 + 64 + cc] + red[256 + 128 + cc] +
               red[256 + 192 + cc];
    atomAddF(&s1[bx + cc], v4);
  }
}

// ---------------------------------------------------------------------------
// gemm_f8 (v9 form, reinstated): 192x192 block tile, 4 waves of 96x96 (3x3
// MFMA), single C plane (kParts=1 — v10/v11's K-split was flat for gemm but
// taxed every downstream C reader with 2x loads/unpacks). 3-buffer
// counted-vmcnt LDS pipeline, grid 256 = 1 block/CU, XCD col-ownership.
static __device__ inline i32x8 ldfragL(const char* p) {
  i32x4 lo = *(const i32x4*)p;
  i32x4 hi = *(const i32x4*)(p + 1024);
  return (i32x8){lo.x, lo.y, lo.z, lo.w, hi.x, hi.y, hi.z, hi.w};
}

__global__ __launch_bounds__(256) void gemm_f8(
    const unsigned char* __restrict__ Ag,
    const unsigned char* __restrict__ Btg,
    unsigned short* __restrict__ Cg) {
  __shared__ char smem[3][24576];
  const int wg = blockIdx.x;
  const int xcd = wg & 7;
  const int idx = wg >> 3;             // 0..31
  const int bxi = xcd * 2 + (idx & 1); // column panel 0..15
  const int byi = idx >> 1;            // row panel    0..15
  const int rowBase = byi * 192, colBase = bxi * 192;

  const int t = threadIdx.x;
  const int w = t >> 6, l = t & 63;
  const int wr = w >> 1, wc = w & 1;
  const int r32 = l & 31, hh = l >> 5;

  f32x16 acc[3][3];
#pragma unroll
  for (int i = 0; i < 3; ++i)
#pragma unroll
    for (int j = 0; j < 3; ++j)
#pragma unroll
      for (int e = 0; e < 16; ++e) acc[i][j][e] = 0.f;

  const unsigned char* aT = Ag + (size_t)rowBase * 64;
  const unsigned char* bT = Btg + (size_t)colBase * 64;
  const int laneOff = r32 * 64 + hh * 32;

  // 24 chunks x 1KB per buffer: q<12 = A (6 row-subtiles x 2 halves),
  // q>=12 = B. Chunk (s,h) at lane slot l*16 holds global bytes
  // {row = s*32 + (l&31), byte = (l>>5)*32 + h*16} — the exact MFMA
  // operand bytes for lane l (verified mapping v7/v9).
#define STAGE(kt, b)                                                        \
  {                                                                         \
    const size_t kOff = (size_t)(kt) * KBLK;                                \
    _Pragma("unroll") for (int r_ = 0; r_ < 6; ++r_) {                      \
      int q_ = r_ * 4 + w;                                                  \
      int qq_ = q_ < 12 ? q_ : q_ - 12;                                     \
      int s_ = qq_ >> 1, h_ = qq_ & 1;                                      \
      const unsigned char* g_ = ((q_ < 12) ? aT : bT) + kOff +              \
                                (size_t)(s_ * 32) * 64 + laneOff + h_ * 16; \
      __builtin_amdgcn_global_load_lds(                                     \
          (const __attribute__((address_space(1))) unsigned*)g_,            \
          (__attribute__((address_space(3))) unsigned*)(smem[b] +           \
                                                        q_ * 1024),         \
          16, 0, 0);                                                        \
    }                                                                       \
  }

  const int nt = NN / 64;  // 48
  STAGE(0, 0);
  STAGE(1, 1);
  for (int kt = 0; kt < nt; ++kt) {
    if (kt < nt - 1) {
      asm volatile("s_waitcnt vmcnt(6)" ::: "memory");
    } else {
      asm volatile("s_waitcnt vmcnt(0)" ::: "memory");
    }
    __builtin_amdgcn_s_barrier();
    __builtin_amdgcn_sched_barrier(0);
    const char* sb = smem[kt % 3];
    i32x8 af[3], bfr[3];
#pragma unroll
    for (int ii = 0; ii < 3; ++ii)
      af[ii] = ldfragL(sb + (wr * 3 + ii) * 2048 + l * 16);
#pragma unroll
    for (int j = 0; j < 3; ++j)
      bfr[j] = ldfragL(sb + 12288 + (wc * 3 + j) * 2048 + l * 16);
    if (kt + 2 < nt) STAGE(kt + 2, (kt + 2) % 3);
    __builtin_amdgcn_s_setprio(1);
#pragma unroll
    for (int ii = 0; ii < 3; ++ii)
#pragma unroll
      for (int j = 0; j < 3; ++j)
        acc[ii][j] = __builtin_amdgcn_mfma_scale_f32_32x32x64_f8f6f4(
            af[ii], bfr[j], acc[ii][j], 0, 0, 0, 127, 0, 127);
    __builtin_amdgcn_s_setprio(0);
    __builtin_amdgcn_sched_barrier(0);
  }
#undef STAGE

  // C/D 32x32 layout: col = lane&31, row = (reg&3) + 8*(reg>>2) + 4*(lane>>5)
#pragma unroll
  for (int i = 0; i < 3; ++i) {
    int rb = rowBase + wr * 96 + i * 32 + 4 * hh;
#pragma unroll
    for (int j = 0; j < 3; ++j) {
      int cc = colBase + wc * 96 + j * 32 + r32;
#pragma unroll
      for (int reg = 0; reg < 16; ++reg) {
        int rr = rb + (reg & 3) + 8 * (reg >> 2);
        Cg[(size_t)rr * NN + cc] = bf16bits(acc[i][j][reg]);
      }
    }
  }
}

// ---------------------------------------------------------------------------
// post1: [0,768)     topk(A2 bf16) + packed fp8 cast -> A2f8
//        [768,1536)  tvec = A.y1 (one wave per row)
__global__ __launch_bounds__(256) void post1(
    const unsigned short* __restrict__ C, const float* __restrict__ A,
    const float* __restrict__ y1, unsigned char* __restrict__ A2f8,
    int* __restrict__ cnts1, int* __restrict__ tIdx1,
    float* __restrict__ tVal1, float* __restrict__ tvec) {
  const int bid = blockIdx.x;
  const int t = threadIdx.x;
  if (bid < 768) {
    int row = bid * 4 + (t >> 6);
    int lane = t & 63;
    float f[48];
    load48_bf(C, row, lane, f);
    // fused packed fp8 cast: f[j*8+e] = col k0+e, k0=(j*64+lane)*8
#pragma unroll
    for (int j = 0; j < 6; ++j) {
      uint2 w;
      w.x = pk4_f8(f[j * 8 + 0] * F8SCALE2, f[j * 8 + 1] * F8SCALE2,
                   f[j * 8 + 2] * F8SCALE2, f[j * 8 + 3] * F8SCALE2);
      w.y = pk4_f8(f[j * 8 + 4] * F8SCALE2, f[j * 8 + 5] * F8SCALE2,
                   f[j * 8 + 6] * F8SCALE2, f[j * 8 + 7] * F8SCALE2);
      size_t addr = (size_t)(j * 8 + (lane >> 3)) * KBLK +
                    (size_t)row * 64 + (lane & 7) * 8;
      *(uint2*)(A2f8 + addr) = w;
    }
    select_compact(f, lane, DESCALE38, 1, &cnts1[row],
                   tIdx1 + (size_t)row * 128, tVal1 + (size_t)row * 128);
  } else {
    int row = (bid - 768) * 4 + (t >> 6);
    int lane = t & 63;
    const float4* rp = (const float4*)(A + (size_t)row * NN);
    const float4* yp = (const float4*)y1;
    float s = 0.f;
#pragma unroll
    for (int j = 0; j < 12; ++j) {
      float4 a = rp[lane + j * 64];
      float4 y = yp[lane + j * 64];
      s += a.x * y.x + a.y * y.y + a.z * y.z + a.w * y.w;
    }
    for (int off = 32; off; off >>= 1) s += __shfl_down(s, off, 64);
    if (lane == 0) tvec[row] = s;
  }
}

// ---------------------------------------------------------------------------
// sel02: phase-homogeneous select kernel (one select per wave, dense waves).
//   bid < 1536, even: layer-2 lists from C (A3 bf16) -> global
//   bid < 1536, odd:  layer-0 lists from A (fp32)    -> global
//   bid == 1536:      post2 fold (w0..w3 -> wacc)
__global__ __launch_bounds__(256) void sel02(
    const unsigned short* __restrict__ C, const float* __restrict__ A,
    int* __restrict__ cnt0, int* __restrict__ idx0, float* __restrict__ val0,
    int* __restrict__ cnt2, int* __restrict__ idx2, float* __restrict__ val2,
    const float* __restrict__ vu, const float* __restrict__ vv,
    const float* __restrict__ y1, const float* __restrict__ s1,
    const float* __restrict__ tvec, float* __restrict__ wacc) {
  __shared__ float red4[4];
  const int bid = blockIdx.x;
  const int t = threadIdx.x;
  if (bid == 1536) {
    float w0 = row_dot_f32(vu, vv, red4);  __syncthreads();
    float w1 = row_dot_f32(vu, y1, red4);  __syncthreads();
    float w2 = row_dot_f32(s1, y1, red4);  __syncthreads();
    float w3 = row_dot_f32(s1, tvec, red4);
    if (t == 0) { wacc[0] = w0; wacc[1] = w1; wacc[2] = w2; wacc[3] = w3; }
    return;
  }
  const int w = t >> 6, lane = t & 63;
  const int row = (bid >> 1) * 4 + w;
  float f[48];
  if ((bid & 1) == 0) {
    load48_bf(C, row, lane, f);
    select_compact(f, lane, DESCALE38, 1, &cnt2[row],
                   idx2 + (size_t)row * 128, val2 + (size_t)row * 128);
  } else {
    load48_f32(A, row, lane, f);
    select_compact(f, lane, 1.0f, 0, &cnt0[row],
                   idx0 + (size_t)row * 128, val0 + (size_t)row * 128);
  }
}

// ---------------------------------------------------------------------------
// gather_light: pure gather, one wave per row (768 blocks x 256 thr).
__global__ __launch_bounds__(256) void gather_light(
    const float* __restrict__ allE, const float* __restrict__ uemb0,
    const float* __restrict__ iemb0, const float* __restrict__ wacc,
    const int* __restrict__ cnt0, const int* __restrict__ idx0,
    const float* __restrict__ val0, const int* __restrict__ cnts1,
    const int* __restrict__ tIdx1, const float* __restrict__ tVal1,
    const int* __restrict__ cnt2, const int* __restrict__ idx2,
    const float* __restrict__ val2, float* __restrict__ lightOut) {
  __shared__ int li[4][384];
  __shared__ float lv[4][384];
  const int t = threadIdx.x;
  const int w = t >> 6, lane = t & 63;
  const int row = blockIdx.x * 4 + w;

  float w0 = wacc[0], w1 = wacc[1], w2 = wacc[2], w3 = wacc[3];
  float ss = w0 + w1 + w2 + w3;
  w0 /= ss; w1 /= ss; w2 /= ss; w3 /= ss;
  float m = fmaxf(fmaxf(w0, w1), fmaxf(w2, w3));
  float ex0 = expf(w0 - m), ex1 = expf(w1 - m), ex2 = expf(w2 - m),
        ex3 = expf(w3 - m);
  float se = ex0 + ex1 + ex2 + ex3;
  float aw0 = ex0 / se, aw1 = ex1 / se, aw2 = ex2 / se, aw3 = ex3 / se;
  float aw4 = GAMMA_F * (aw1 + aw2 + aw3);

  const int c0 = cnt0[row], c1 = cnts1[row], c2 = cnt2[row];
  const int p0 = (c0 + 7) & ~7, p1 = (c1 + 7) & ~7, p2 = (c2 + 7) & ~7;
  int* Li = li[w];
  float* Lv = lv[w];
  const size_t rb = (size_t)row * 128;
  for (int k = lane; k < p0; k += 64) {
    bool in = k < c0;
    Li[k] = in ? idx0[rb + k] : 0;
    Lv[k] = in ? aw1 * val0[rb + k] : 0.f;
  }
  for (int k = lane; k < p1; k += 64) {
    bool in = k < c1;
    Li[p0 + k] = in ? tIdx1[rb + k] : 0;
    Lv[p0 + k] = in ? aw2 * tVal1[rb + k] : 0.f;
  }
  for (int k = lane; k < p2; k += 64) {
    bool in = k < c2;
    Li[p0 + p1 + k] = in ? idx2[rb + k] : 0;
    Lv[p0 + p1 + k] = in ? aw3 * val2[rb + k] : 0.f;
  }
  // same-wave produce->consume through LDS: compiler orders via lgkmcnt.

  const int ct = p0 + p1 + p2;
  const float2* E2 = (const float2*)allE;
  float ax = 0.f, ay = 0.f, bx_ = 0.f, by_ = 0.f;
  for (int k = 0; k < ct; k += 8) {
    int i0 = Li[k + 0], i1 = Li[k + 1], i2 = Li[k + 2], i3 = Li[k + 3];
    int i4 = Li[k + 4], i5 = Li[k + 5], i6 = Li[k + 6], i7 = Li[k + 7];
    float v0 = Lv[k + 0], v1 = Lv[k + 1], v2 = Lv[k + 2], v3 = Lv[k + 3];
    float v4 = Lv[k + 4], v5 = Lv[k + 5], v6 = Lv[k + 6], v7 = Lv[k + 7];
    float2 g0 = E2[(i0 >> 1) + lane];
    float2 g1 = E2[(i1 >> 1) + lane];
    float2 g2 = E2[(i2 >> 1) + lane];
    float2 g3 = E2[(i3 >> 1) + lane];
    float2 g4 = E2[(i4 >> 1) + lane];
    float2 g5 = E2[(i5 >> 1) + lane];
    float2 g6 = E2[(i6 >> 1) + lane];
    float2 g7 = E2[(i7 >> 1) + lane];
    ax += v0 * g0.x; ay += v0 * g0.y;
    bx_ += v1 * g1.x; by_ += v1 * g1.y;
    ax += v2 * g2.x; ay += v2 * g2.y;
    bx_ += v3 * g3.x; by_ += v3 * g3.y;
    ax += v4 * g4.x; ay += v4 * g4.y;
    bx_ += v5 * g5.x; by_ += v5 * g5.y;
    ax += v6 * g6.x; ay += v6 * g6.y;
    bx_ += v7 * g7.x; by_ += v7 * g7.y;
  }
  float2 sE = E2[((size_t)row << 6) + lane];
  float2 e0 = (row < NU)
                  ? ((const float2*)uemb0)[(size_t)row * 64 + lane]
                  : ((const float2*)iemb0)[(size_t)(row - NU) * 64 + lane];
  float ox = (ax + bx_) + aw0 * sE.x + aw4 * e0.x;
  float oy = (ay + by_) + aw0 * sE.y + aw4 * e0.y;
  float2 o; o.x = ox; o.y = oy;
  ((float2*)lightOut)[(size_t)row * 64 + lane] = o;
}

__global__ __launch_bounds__(256) void out_dot(const int* __restrict__ users,
                                               const int* __restrict__ items,
                                               const float* __restrict__ lightOut,
                                               float* __restrict__ out) {
  int b = blockIdx.x * 4 + (threadIdx.x >> 6);
  int lane = threadIdx.x & 63;
  const float* up = lightOut + (size_t)users[b] * DD;
  const float* ip = lightOut + (size_t)(NU + items[b]) * DD;
  float s = up[lane] * ip[lane] + up[lane + 64] * ip[lane + 64];
  for (int off = 32; off; off >>= 1) s += __shfl_down(s, off, 64);
  if (lane == 0) out[b] = s;
}

// ---------------------------------------------------------------------------
extern "C" void kernel_launch(void* const* d_in, const int* in_sizes, int n_in,
                              void* d_out, int out_size, void* d_ws,
                              size_t ws_size, hipStream_t stream) {
  const int* users = (const int*)d_in[0];
  const int* items = (const int*)d_in[1];
  const float* A = (const float*)d_in[2];
  const float* uemb = (const float*)d_in[3];
  const float* iemb = (const float*)d_in[4];
  const float* uemb0 = (const float*)d_in[5];
  const float* iemb0 = (const float*)d_in[6];
  const float* vu = (const float*)d_in[7];
  const float* vv = (const float*)d_in[8];
  float* out = (float*)d_out;

  char* ws = (char*)d_ws;
  size_t off = 0;
  auto alloc = [&](size_t bytes) -> void* {
    void* p = ws + off;
    off += (bytes + 255) & ~(size_t)255;
    return p;
  };
  unsigned char* Af8 = (unsigned char*)alloc((size_t)NN * NN);
  unsigned char* Atf8 = (unsigned char*)alloc((size_t)NN * NN);
  unsigned char* A2f8 = (unsigned char*)alloc((size_t)NN * NN);
  float* y1 = (float*)alloc((size_t)NN * 4);   // contiguous with s1
  float* s1 = (float*)alloc((size_t)NN * 4);
  float* tvec = (float*)alloc((size_t)NN * 4);
  float* wacc = (float*)alloc(256);
  int* cnts1 = (int*)alloc((size_t)NN * 4);
  int* tIdx1 = (int*)alloc((size_t)NN * 128 * 4);
  float* tVal1 = (float*)alloc((size_t)NN * 128 * 4);
  float* lightOut = (float*)alloc((size_t)NN * DD * 4);
  int* cnt0 = (int*)alloc((size_t)NN * 4);
  int* cnt2 = (int*)alloc((size_t)NN * 4);
  float* allE = (float*)alloc((size_t)NN * DD * 4);  // dedicated (no alias)

  // layer-0/2 lists (4 x 1.5 MB) alias Atf8 (9.4 MB): Atf8 is dead after
  // gemm#2 (step 5); sel02 (step 6) writes, gather (step 8) reads.
  const size_t LSTB = (size_t)NN * 128 * 4;
  int* idx0 = (int*)(Atf8);
  float* val0 = (float*)(Atf8 + LSTB);
  int* idx2 = (int*)(Atf8 + 2 * LSTB);
  float* val2 = (float*)(Atf8 + 3 * LSTB);

  // single-plane bf16 C (kParts=1: downstream reads/unpacks halved)
  unsigned short* C = (unsigned short*)alloc((size_t)NN * NN * 2);

  // 1) zero y1/s1 (contiguous 2*NN floats)
  hipMemsetAsync(y1, 0, (size_t)2 * NN * 4, stream);
  // 2) prep: A -> packed fp8 (reg-direct straight pack + LDS transpose) |
  //    y1/s1 partials | emb concat
  prep<<<2688, 256, 0, stream>>>(A, vu, vv, Af8, Atf8, y1, s1, uemb, iemb,
                                 allE);
  // 3) A2 = A*A (192-tile 3x3-wave pipelined MX fp8 MFMA, grid 256 = 1/CU)
  gemm_f8<<<256, 256, 0, stream>>>(Af8, Atf8, C);
  // 4) post1: topk(A2, adaptive radix + prefix compact)+fp8 cast | tvec=A.y1
  post1<<<1536, 256, 0, stream>>>(C, A, y1, A2f8, cnts1, tIdx1, tVal1, tvec);
  // 5) A3 = A2*A (overwrite C)
  gemm_f8<<<256, 256, 0, stream>>>(A2f8, Atf8, C);
  // 6) sel02: layer-0 (A) + layer-2 (A3) top-64 lists | post2 fold (bid 1536)
  sel02<<<1537, 256, 0, stream>>>(C, A, cnt0, idx0, val0, cnt2, idx2, val2,
                                  vu, vv, y1, s1, tvec, wacc);
  // 7) gather_light: pure float2 gather, one wave per row
  gather_light<<<768, 256, 0, stream>>>(allE, uemb0, iemb0, wacc, cnt0, idx0,
                                        val0, cnts1, tIdx1, tVal1, cnt2, idx2,
                                        val2, lightOut);
  // 8) gather dots
  out_dot<<<BB / 4, 256, 0, stream>>>(users, items, lightOut, out);
}